// Round 7
// baseline (146.609 us; speedup 1.0000x reference)
//
#include <hip/hip_runtime.h>
#include <hip/hip_bf16.h>
#include <math.h>
#include <limits.h>

// Problem dims
constexpr int NB    = 4096;   // batch
constexpr int ROWS2 = NB * 12;            // 49152 rows for the 2->100->100->2 MLPs
constexpr int G2_BLOCKS = ROWS2 / 64;     // 768 (64 rows/block)
constexpr int TBL_CAP = 48;               // lattice slots per channel

// workspace layout (float offsets)
constexpr size_t WS_Y1    = 0;              // NB*24
constexpr size_t WS_YHAT  = 98304;          // NB*24
constexpr size_t WS_YHAT1 = 196608;         // NB*24
constexpr size_t WS_U2T   = 294936;         // 24*256 (transposed: [c][m])
constexpr size_t WS_EB    = 301080;         // 24*58 precomputed prior params
constexpr size_t WS_KMM   = 302472;         // 48 ints (kmin[24], kmax[24])
constexpr size_t WS_PART  = 302520;         // 768*24 per-block mean partials
constexpr size_t WS_W1T   = 320952;         // 4 x [100][128] transposed w1 (51200)
constexpr size_t WS_TBL   = 372152;         // 24*48*256 table of log(pdf+1e-9)
constexpr size_t WS_END   = WS_TBL + 24 * TBL_CAP * 256;   // 667064 floats (~2.67 MB)

constexpr float STEP_ODD = 0.8660254037844386f;   // sqrt(3)/2
constexpr float INV_ODD  = 1.1547005383792517f;   // 2/sqrt(3)

__device__ __forceinline__ float lrelu(float x) { return x >= 0.f ? x : 0.01f * x; }
__device__ __forceinline__ float rcp_fast(float x) { return __builtin_amdgcn_rcpf(x); }

__device__ __forceinline__ float tanh_fast(float x) {
    float xx = fminf(fmaxf(x, -15.f), 15.f);
    float e = __expf(xx + xx);
    return fmaf(-2.f, rcp_fast(e + 1.f), 1.f);
}
__device__ __forceinline__ float splus(float x) {
    return fmaxf(x, 0.f) + __logf(1.f + __expf(-fabsf(x)));
}
__device__ __forceinline__ float splus_precise(float x) {
    return fmaxf(x, 0.f) + log1pf(expf(-fabsf(x)));
}

__device__ __forceinline__ void fma4(float4& a, float h, const float4& w) {
    a.x = fmaf(h, w.x, a.x); a.y = fmaf(h, w.y, a.y);
    a.z = fmaf(h, w.z, a.z); a.w = fmaf(h, w.w, a.w);
}

// exact A2 hex lattice nearest-point quantizer; matches jnp.round (rint = RNE)
__device__ __forceinline__ void hexq(float p0, float p1, float& q0, float& q1) {
    const float S3 = 1.7320508075688772f;
    const float H3 = 0.8660254037844386f;
    float c00 = rintf(p0);
    float c01 = rintf(p1 / S3) * S3;
    float c10 = rintf(p0 - 0.5f) + 0.5f;
    float c11 = rintf((p1 - H3) / S3) * S3 + H3;
    float d0 = (p0 - c00) * (p0 - c00) + (p1 - c01) * (p1 - c01);
    float d1 = (p0 - c10) * (p0 - c10) + (p1 - c11) * (p1 - c11);
    bool take0 = d0 <= d1;
    q0 = take0 ? c00 : c10;
    q1 = take0 ? c01 : c11;
}

// per-channel prior chain: log(pdf + 1e-9) at point p, params P (58 floats)
__device__ __forceinline__ float logpdf_ch(const float* __restrict__ P, float p) {
    float w00 = P[0], w01 = P[1], w02 = P[2];
    float z0 = fmaf(w00, p, P[3]);
    float z1 = fmaf(w01, p, P[4]);
    float z2 = fmaf(w02, p, P[5]);
    float a0 = P[6], a1 = P[7], a2 = P[8];
    float e0 = tanh_fast(z0), e1 = tanh_fast(z1), e2 = tanh_fast(z2);
    float h0 = fmaf(a0, e0, z0), h1 = fmaf(a1, e1, z1), h2 = fmaf(a2, e2, z2);
    float t0 = w00 * fmaf(a0, fmaf(-e0, e0, 1.f), 1.f);
    float t1 = w01 * fmaf(a1, fmaf(-e1, e1, 1.f), 1.f);
    float t2 = w02 * fmaf(a2, fmaf(-e2, e2, 1.f), 1.f);

#define EB_LAYER(O)                                                            \
    {                                                                          \
        float z0n = fmaf(P[O+0], h0, fmaf(P[O+1], h1, fmaf(P[O+2], h2, P[O+9])));  \
        float z1n = fmaf(P[O+3], h0, fmaf(P[O+4], h1, fmaf(P[O+5], h2, P[O+10]))); \
        float z2n = fmaf(P[O+6], h0, fmaf(P[O+7], h1, fmaf(P[O+8], h2, P[O+11]))); \
        float s0 = fmaf(P[O+0], t0, fmaf(P[O+1], t1, P[O+2] * t2));            \
        float s1 = fmaf(P[O+3], t0, fmaf(P[O+4], t1, P[O+5] * t2));            \
        float s2 = fmaf(P[O+6], t0, fmaf(P[O+7], t1, P[O+8] * t2));            \
        float g0 = P[O+12], g1 = P[O+13], g2 = P[O+14];                        \
        float q0 = tanh_fast(z0n), q1 = tanh_fast(z1n), q2 = tanh_fast(z2n);   \
        h0 = fmaf(g0, q0, z0n); h1 = fmaf(g1, q1, z1n); h2 = fmaf(g2, q2, z2n); \
        t0 = s0 * fmaf(g0, fmaf(-q0, q0, 1.f), 1.f);                           \
        t1 = s1 * fmaf(g1, fmaf(-q1, q1, 1.f), 1.f);                           \
        t2 = s2 * fmaf(g2, fmaf(-q2, q2, 1.f), 1.f);                           \
    }
    EB_LAYER(9)
    EB_LAYER(24)
    EB_LAYER(39)
#undef EB_LAYER

    float L = fmaf(P[54], h0, fmaf(P[55], h1, fmaf(P[56], h2, P[57])));
    float T = fmaf(P[54], t0, fmaf(P[55], t1, P[56] * t2));
    float Lc = fminf(fmaxf(L, -30.f), 30.f);
    float sg = rcp_fast(1.f + __expf(-Lc));
    float pdf = sg * (1.f - sg) * T;
    return __logf(pdf + 1e-9f);
}

// ---------------------------------------------------------------------------
// K0: block 0: prior params + u2^T + kmm init.
//     blocks 1..200: transpose the four 100x100 W1 matrices into [100][128]
// ---------------------------------------------------------------------------
__global__ __launch_bounds__(256) void k_prep(
    const float* __restrict__ H0p, const float* __restrict__ H1p,
    const float* __restrict__ H2p, const float* __restrict__ H3p,
    const float* __restrict__ H4p,
    const float* __restrict__ b0p, const float* __restrict__ b1p,
    const float* __restrict__ b2p, const float* __restrict__ b3p,
    const float* __restrict__ b4p,
    const float* __restrict__ a0p, const float* __restrict__ a1p,
    const float* __restrict__ a2p, const float* __restrict__ a3p,
    const float* __restrict__ u,
    const float* __restrict__ w1ga, const float* __restrict__ w1gac,
    const float* __restrict__ w1gsc, const float* __restrict__ w1gs,
    float* __restrict__ eb, float* __restrict__ u2t,
    int* __restrict__ kmm, float* __restrict__ w1t)
{
    int tid = threadIdx.x;
    if (blockIdx.x > 0) {
        int t = blockIdx.x - 1;             // 0..199
        int m = t / 50;
        int o = (t % 50) * 256 + tid;       // 0..12799
        int k = o >> 7, i = o & 127;
        const float* src = (m == 0) ? w1ga : (m == 1) ? w1gac
                         : (m == 2) ? w1gsc : w1gs;
        w1t[m * 12800 + o] = (i < 100) ? src[i * 100 + k] : 0.f;
        return;
    }
    if (tid < 24) {
        int c = tid;
        float* P = eb + c * 58;
        for (int j = 0; j < 3; ++j) P[j]      = splus_precise(H0p[c*3+j]);
        for (int j = 0; j < 3; ++j) P[3+j]    = b0p[c*3+j];
        for (int j = 0; j < 3; ++j) P[6+j]    = tanhf(a0p[c*3+j]);
        for (int j = 0; j < 9; ++j) P[9+j]    = splus_precise(H1p[c*9+j]);
        for (int j = 0; j < 3; ++j) P[18+j]   = b1p[c*3+j];
        for (int j = 0; j < 3; ++j) P[21+j]   = tanhf(a1p[c*3+j]);
        for (int j = 0; j < 9; ++j) P[24+j]   = splus_precise(H2p[c*9+j]);
        for (int j = 0; j < 3; ++j) P[33+j]   = b2p[c*3+j];
        for (int j = 0; j < 3; ++j) P[36+j]   = tanhf(a2p[c*3+j]);
        for (int j = 0; j < 9; ++j) P[39+j]   = splus_precise(H3p[c*9+j]);
        for (int j = 0; j < 3; ++j) P[48+j]   = b3p[c*3+j];
        for (int j = 0; j < 3; ++j) P[51+j]   = tanhf(a3p[c*3+j]);
        for (int j = 0; j < 3; ++j) P[54+j]   = splus_precise(H4p[c*3+j]);
        P[57] = b4p[c];
        kmm[tid]      = INT_MAX;
        kmm[24 + tid] = INT_MIN;
    }
    int m = tid;
    if (m < 256) {
        for (int j = 0; j < 12; ++j) {
            float a  = u[m*24 + 2*j];
            float bb = u[m*24 + 2*j + 1];
            float p0 = fmaf(0.5f, bb, a);
            float p1 = 0.8660254037844386f * bb;
            float q0, q1; hexq(p0, p1, q0, q1);
            u2t[(2*j)   * 256 + m] = p0 - q0;
            u2t[(2*j+1) * 256 + m] = p1 - q1;
        }
    }
}

// ---------------------------------------------------------------------------
// gemm2 body (shared by k_gemm2<1> and the merged gs+table kernel).
// 2 -> 100 (lrelu) -> 100 (lrelu) -> 2, register-tiled, weights from L2
// (pre-transposed w1t [100][128]); only h0^T (25.6 KB) in LDS.
// ---------------------------------------------------------------------------
template <int MEAN>
__device__ __forceinline__ void gemm2_body(
    int bid,
    const float* __restrict__ in,
    const float* __restrict__ w0, const float* __restrict__ b0,
    const float* __restrict__ w1t,
    const float* __restrict__ b1, const float* __restrict__ w2,
    const float* __restrict__ b2,
    float* __restrict__ out, float* __restrict__ partial)
{
    __shared__ alignas(16) float shT[100 * 64];   // h0T [k][row]; reused as red
    __shared__ float S[64][2];

    int tid = threadIdx.x;
    int row0 = bid * 64;

    int lrow = tid & 63, jg = tid >> 6;
    float2 xv = ((const float2*)in)[row0 + lrow];
#pragma unroll
    for (int jj = 0; jj < 25; ++jj) {
        int j = jg * 25 + jj;
        shT[j * 64 + lrow] =
            lrelu(fmaf(w0[2*j], xv.x, fmaf(w0[2*j+1], xv.y, b0[j])));
    }

    int lane = tid & 63, wv = tid >> 6;
    int ct = lane & 31;                 // col group: cols 4ct..4ct+3 of 128
    int rt = wv * 2 + (lane >> 5);      // row group: rows 8rt..8rt+7
    bool cvalid = (4 * ct < 100);
    float4 zero4 = make_float4(0.f, 0.f, 0.f, 0.f);
    float4 b14 = cvalid ? *(const float4*)(b1 + 4*ct) : zero4;
    float4 w20 = cvalid ? *(const float4*)(w2 + 4*ct) : zero4;
    float4 w21 = cvalid ? *(const float4*)(w2 + 100 + 4*ct) : zero4;
    __syncthreads();

    float4 acc[8];
#pragma unroll
    for (int r = 0; r < 8; ++r) acc[r] = zero4;
    const float4* wg  = (const float4*)w1t + ct;   // +32 float4 per k
    const float4* hT4 = (const float4*)shT;        // [100][16]
#pragma unroll 4
    for (int k = 0; k < 100; ++k) {
        float4 w4 = wg[k * 32];
        float4 ha = hT4[k * 16 + rt * 2];
        float4 hb = hT4[k * 16 + rt * 2 + 1];
        fma4(acc[0], ha.x, w4); fma4(acc[1], ha.y, w4);
        fma4(acc[2], ha.z, w4); fma4(acc[3], ha.w, w4);
        fma4(acc[4], hb.x, w4); fma4(acc[5], hb.y, w4);
        fma4(acc[6], hb.z, w4); fma4(acc[7], hb.w, w4);
    }
    __syncthreads();          // h reads done; reuse shT as reduction pad

    float* red = shT;         // [64][2][32]
#pragma unroll
    for (int r = 0; r < 8; ++r) {
        float a0 = lrelu(acc[r].x + b14.x);
        float a1 = lrelu(acc[r].y + b14.y);
        float a2 = lrelu(acc[r].z + b14.z);
        float a3 = lrelu(acc[r].w + b14.w);
        float y0 = fmaf(a0, w20.x, fmaf(a1, w20.y, fmaf(a2, w20.z, a3 * w20.w)));
        float y1 = fmaf(a0, w21.x, fmaf(a1, w21.y, fmaf(a2, w21.z, a3 * w21.w)));
        int row = rt * 8 + r;
        red[(row * 2) * 32 + ct]     = y0;
        red[(row * 2 + 1) * 32 + ct] = y1;
    }
    __syncthreads();
    if (tid < 128) {
        int row = tid >> 1, p = tid & 1;
        const float4* rp = (const float4*)&red[(row * 2 + p) * 32];
        float s = 0.f;
#pragma unroll
        for (int g = 0; g < 8; ++g) {
            float4 v = rp[g];
            s += (v.x + v.y) + (v.z + v.w);
        }
        float y = s + b2[p];
        out[(row0 + row) * 2 + p] = y;
        if (MEAN) S[row][p] = y;
    }
    if (MEAN) {
        __syncthreads();
        if (tid < 24) {
            int j = tid >> 1, par = tid & 1;
            int base = row0 % 12;
            int k0 = (j - base + 12) % 12;
            float s = 0.f;
            for (int k = k0; k < 64; k += 12) s += S[k][par];
            partial[bid * 24 + tid] = s;
        }
    }
}

__global__ __launch_bounds__(256, 4) void k_gemm2_mean(
    const float* __restrict__ in,
    const float* __restrict__ w0, const float* __restrict__ b0,
    const float* __restrict__ w1t,
    const float* __restrict__ b1, const float* __restrict__ w2,
    const float* __restrict__ b2,
    float* __restrict__ out, float* __restrict__ partial)
{
    gemm2_body<1>(blockIdx.x, in, w0, b0, w1t, b1, w2, b2, out, partial);
}

// ---------------------------------------------------------------------------
// K3: FUSED coupled transforms, high-parallelism version.
// 4 rows/block, 1024 blocks (4/CU, 16 waves/CU). Each block first computes
// the EMA mean ym from the 768 per-block partials (identical fixed order ->
// bit-identical across blocks). Pass A: yhat = hexq(gac(y1-ym)) + kmm.
// Pass B: yhat1 = gsc(yhat) + ym. Layer-1: thread (rg,i) covers 2 rows,
// w1t reads coalesced, h0 reads wave-uniform broadcast.
// ---------------------------------------------------------------------------
__global__ __launch_bounds__(256, 4) void k_fused24(
    const float* __restrict__ y1,
    const float* __restrict__ w0A, const float* __restrict__ w1tA,
    const float* __restrict__ w2A,
    const float* __restrict__ w0B, const float* __restrict__ w1tB,
    const float* __restrict__ w2B,
    const float* __restrict__ partial, const float* __restrict__ y_mean,
    float* __restrict__ yhat, float* __restrict__ yhat1,
    int* __restrict__ kmm)
{
    __shared__ float sX[4 * 25];
    __shared__ float sO[4 * 25];
    __shared__ alignas(8) float h0[100 * 4];   // [j][r]
    __shared__ float h1[100 * 4];              // [i][r]
    __shared__ float ymL[24];
    __shared__ int kminL[24], kmaxL[24];

    int tid = threadIdx.x;
    int row0 = blockIdx.x * 4;

    // in-block EMA mean (fixed order, identical in every block)
    {
        int c = tid >> 3, s = tid & 7;
        float v = 0.f;
        if (c < 24)
            for (int g = s; g < G2_BLOCKS; g += 8) v += partial[g * 24 + c];
        v += __shfl_xor(v, 1); v += __shfl_xor(v, 2); v += __shfl_xor(v, 4);
        if (c < 24 && s == 0)
            ymL[c] = fmaf(0.05f, y_mean[c], 0.95f * (v * (1.0f / NB)));
    }
    if (tid < 24) { kminL[tid] = INT_MAX; kmaxL[tid] = INT_MIN; }
    __syncthreads();

    // pass-A input: y1 - ym
    for (int e = tid; e < 96; e += 256) {
        int r = e / 24, c = e - r * 24;
        sX[r * 25 + c] = y1[row0 * 24 + e] - ymL[c];
    }

    int rg = tid >> 7, ii = tid & 127;

    for (int pass = 0; pass < 2; ++pass) {
        const float* w0  = pass ? w0B  : w0A;
        const float* w1t = pass ? w1tB : w1tA;
        const float* w2  = pass ? w2B  : w2A;
        __syncthreads();   // sX ready (pass A: fill; pass B: hexq rewrite)

        // layer 0: h0[j][r], 400 outputs
        for (int e = tid; e < 400; e += 256) {
            int j = e >> 2, r = e & 3;
            const float* wr = w0 + j * 24;
            const float* xr = sX + r * 25;
            float a = 0.f, b = 0.f;
#pragma unroll
            for (int k = 0; k < 24; k += 2) {
                a = fmaf(wr[k],     xr[k],     a);
                b = fmaf(wr[k + 1], xr[k + 1], b);
            }
            h0[j * 4 + r] = splus(a + b);
        }
        __syncthreads();

        // layer 1: thread (rg, ii) -> z1[ii] for rows 2rg, 2rg+1
        {
            float a0 = 0.f, a1 = 0.f;
            const float* wc = w1t + ii;
#pragma unroll 4
            for (int j = 0; j < 100; ++j) {
                float w = wc[j * 128];
                float2 h = *(const float2*)&h0[j * 4 + rg * 2];
                a0 = fmaf(w, h.x, a0);
                a1 = fmaf(w, h.y, a1);
            }
            if (ii < 100) {
                h1[ii * 4 + rg * 2]     = splus(a0);
                h1[ii * 4 + rg * 2 + 1] = splus(a1);
            }
        }
        __syncthreads();

        // layer 2: 96 outputs
        for (int e = tid; e < 96; e += 256) {
            int c = e >> 2, r = e & 3;
            const float* w2r = w2 + c * 100;
            float s = 0.f, s2 = 0.f;
#pragma unroll 4
            for (int i = 0; i < 100; i += 2) {
                s  = fmaf(w2r[i],     h1[i * 4 + r],       s);
                s2 = fmaf(w2r[i + 1], h1[(i + 1) * 4 + r], s2);
            }
            float v = s + s2;
            if (pass == 0) sO[r * 25 + c] = v;
            else yhat1[(row0 + r) * 24 + c] = v + ymL[c];
        }

        if (pass == 0) {
            __syncthreads();
            for (int e = tid; e < 48; e += 256) {
                int pr = e >> 2, r = e & 3;
                float v0 = sO[r * 25 + 2*pr], v1 = sO[r * 25 + 2*pr + 1];
                float q0, q1; hexq(v0, v1, q0, q1);
                yhat[(row0 + r) * 24 + 2*pr]     = q0;
                yhat[(row0 + r) * 24 + 2*pr + 1] = q1;
                sX[r * 25 + 2*pr]     = q0;       // pass-B input
                sX[r * 25 + 2*pr + 1] = q1;
                int k0 = (int)rintf(q0 * 2.0f);
                int k1 = (int)rintf(q1 * INV_ODD);
                atomicMin(&kminL[2*pr], k0);     atomicMax(&kmaxL[2*pr], k0);
                atomicMin(&kminL[2*pr + 1], k1); atomicMax(&kmaxL[2*pr + 1], k1);
            }
        }
    }
    __syncthreads();
    if (tid < 24) {
        atomicMin(&kmm[tid], kminL[tid]);
        atomicMax(&kmm[24 + tid], kmaxL[tid]);
    }
}

// ---------------------------------------------------------------------------
// K4: merged dispatch: blocks [0,768) = gs GEMM (xhat), blocks [768,1920) =
// prior table build. Both depend only on k_fused24.
// ---------------------------------------------------------------------------
__global__ __launch_bounds__(256, 4) void k_gs_table(
    const float* __restrict__ yhat1,
    const float* __restrict__ w0, const float* __restrict__ b0,
    const float* __restrict__ w1t,
    const float* __restrict__ b1, const float* __restrict__ w2,
    const float* __restrict__ b2, float* __restrict__ xhat,
    const float* __restrict__ eb, const float* __restrict__ u2t,
    const int* __restrict__ kmm, float* __restrict__ tbl)
{
    if (blockIdx.x < (unsigned)G2_BLOCKS) {
        gemm2_body<0>(blockIdx.x, yhat1, w0, b0, w1t, b1, w2, b2, xhat, nullptr);
    } else {
        int cv = blockIdx.x - G2_BLOCKS;
        int c = cv / TBL_CAP, v = cv - c * TBL_CAP;
        int m = threadIdx.x;
        float step = (c & 1) ? STEP_ODD : 0.5f;
        float val = (float)(kmm[c] + v) * step;
        float p = val + u2t[c * 256 + m];
        tbl[cv * 256 + m] = logpdf_ch(eb + c * 58, p);
    }
}

// ---------------------------------------------------------------------------
// K5: MC likelihood via table gather; shuffle-based logsumexp.
// ---------------------------------------------------------------------------
__global__ __launch_bounds__(256) void k_mc_tbl(
    const float* __restrict__ yhat, const float* __restrict__ u2t,
    const float* __restrict__ eb, const int* __restrict__ kmm,
    const float* __restrict__ tbl, float* __restrict__ lik)
{
    __shared__ float redm[4], reds[4];
    int tid = threadIdx.x;
    int wv = tid >> 6;
    int b = blockIdx.x;

    float y[24];
    const float4* yr = (const float4*)(yhat + b * 24);
#pragma unroll
    for (int k4 = 0; k4 < 6; ++k4) {
        float4 t = yr[k4];
        y[4*k4] = t.x; y[4*k4+1] = t.y; y[4*k4+2] = t.z; y[4*k4+3] = t.w;
    }

    float lp = 0.f;
    unsigned miss = 0;
#pragma unroll
    for (int c = 0; c < 24; ++c) {
        float inv = (c & 1) ? INV_ODD : 2.0f;
        int k = (int)rintf(y[c] * inv);
        int idx = k - kmm[c];
        if (idx >= 0 && idx < TBL_CAP)
            lp += tbl[(c * TBL_CAP + idx) * 256 + tid];
        else
            miss |= (1u << c);
    }
    while (miss) {   // rare fallback: channel exceeded TBL_CAP lattice slots
        int c = __ffs(miss) - 1;
        miss &= miss - 1;
        lp += logpdf_ch(eb + c * 58, y[c] + u2t[c * 256 + tid]);
    }

    float m = lp;
#pragma unroll
    for (int off = 1; off < 64; off <<= 1) m = fmaxf(m, __shfl_xor(m, off));
    if ((tid & 63) == 0) redm[wv] = m;
    __syncthreads();
    float mx = fmaxf(fmaxf(redm[0], redm[1]), fmaxf(redm[2], redm[3]));
    float e = __expf(lp - mx);
#pragma unroll
    for (int off = 1; off < 64; off <<= 1) e += __shfl_xor(e, off);
    if ((tid & 63) == 0) reds[wv] = e;
    __syncthreads();
    if (tid == 0)
        lik[b] = mx + __logf(reds[0] + reds[1] + reds[2] + reds[3])
               - 7.271269879190247f;  // -log(NMC) + LOG_VOL
}

// ---------------------------------------------------------------------------
// K5 fallback (ws too small): direct MC
// ---------------------------------------------------------------------------
__global__ __launch_bounds__(256) void k_mc_direct(
    const float* __restrict__ yhat, const float* __restrict__ u2t,
    const float* __restrict__ eb, float* __restrict__ lik)
{
    __shared__ alignas(16) float sU[24 * 256];
    __shared__ float redm[4], reds[4];
    int tid = threadIdx.x;
    int wv = tid >> 6;
    int b = blockIdx.x;
    for (int i = tid; i < 1536; i += 256)
        ((float4*)sU)[i] = ((const float4*)u2t)[i];
    __syncthreads();

    float lp = 0.f;
    for (int c = 0; c < 24; ++c)
        lp += logpdf_ch(eb + c * 58, yhat[b * 24 + c] + sU[c * 256 + tid]);

    float m = lp;
#pragma unroll
    for (int off = 1; off < 64; off <<= 1) m = fmaxf(m, __shfl_xor(m, off));
    if ((tid & 63) == 0) redm[wv] = m;
    __syncthreads();
    float mx = fmaxf(fmaxf(redm[0], redm[1]), fmaxf(redm[2], redm[3]));
    float e = __expf(lp - mx);
#pragma unroll
    for (int off = 1; off < 64; off <<= 1) e += __shfl_xor(e, off);
    if ((tid & 63) == 0) reds[wv] = e;
    __syncthreads();
    if (tid == 0)
        lik[b] = mx + __logf(reds[0] + reds[1] + reds[2] + reds[3])
               - 7.271269879190247f;
}

// ---------------------------------------------------------------------------
extern "C" void kernel_launch(void* const* d_in, const int* in_sizes, int n_in,
                              void* d_out, int out_size, void* d_ws, size_t ws_size,
                              hipStream_t stream)
{
    (void)in_sizes; (void)n_in; (void)out_size;
    const float* x      = (const float*)d_in[0];
    const float* y_mean = (const float*)d_in[1];
    const float* u      = (const float*)d_in[2];
    const float* ga_w0  = (const float*)d_in[3];
    const float* ga_b0  = (const float*)d_in[4];
    const float* ga_w1  = (const float*)d_in[5];
    const float* ga_b1  = (const float*)d_in[6];
    const float* ga_w2  = (const float*)d_in[7];
    const float* ga_b2  = (const float*)d_in[8];
    const float* gs_w0  = (const float*)d_in[9];
    const float* gs_b0  = (const float*)d_in[10];
    const float* gs_w1  = (const float*)d_in[11];
    const float* gs_b1  = (const float*)d_in[12];
    const float* gs_w2  = (const float*)d_in[13];
    const float* gs_b2  = (const float*)d_in[14];
    const float* gac_w0 = (const float*)d_in[15];
    const float* gac_w1 = (const float*)d_in[16];
    const float* gac_w2 = (const float*)d_in[17];
    const float* gsc_w0 = (const float*)d_in[18];
    const float* gsc_w1 = (const float*)d_in[19];
    const float* gsc_w2 = (const float*)d_in[20];
    const float* eb_H0  = (const float*)d_in[21];
    const float* eb_H1  = (const float*)d_in[22];
    const float* eb_H2  = (const float*)d_in[23];
    const float* eb_H3  = (const float*)d_in[24];
    const float* eb_H4  = (const float*)d_in[25];
    const float* eb_b0  = (const float*)d_in[26];
    const float* eb_b1  = (const float*)d_in[27];
    const float* eb_b2  = (const float*)d_in[28];
    const float* eb_b3  = (const float*)d_in[29];
    const float* eb_b4  = (const float*)d_in[30];
    const float* eb_a0  = (const float*)d_in[31];
    const float* eb_a1  = (const float*)d_in[32];
    const float* eb_a2  = (const float*)d_in[33];
    const float* eb_a3  = (const float*)d_in[34];

    float* ws    = (float*)d_ws;
    float* y1    = ws + WS_Y1;
    float* yhat  = ws + WS_YHAT;
    float* yhat1 = ws + WS_YHAT1;
    float* u2t   = ws + WS_U2T;
    float* eb    = ws + WS_EB;
    int*   kmm   = (int*)(ws + WS_KMM);
    float* part  = ws + WS_PART;
    float* w1t   = ws + WS_W1T;
    float* tbl   = ws + WS_TBL;
    float* xhat  = (float*)d_out;
    float* lik   = (float*)d_out + 98304;

    float* w1tGA  = w1t;
    float* w1tGAC = w1t + 12800;
    float* w1tGSC = w1t + 25600;
    float* w1tGS  = w1t + 38400;

    bool use_tbl = ws_size >= WS_END * sizeof(float);

    k_prep<<<201, 256, 0, stream>>>(eb_H0, eb_H1, eb_H2, eb_H3, eb_H4,
                                    eb_b0, eb_b1, eb_b2, eb_b3, eb_b4,
                                    eb_a0, eb_a1, eb_a2, eb_a3, u,
                                    ga_w1, gac_w1, gsc_w1, gs_w1,
                                    eb, u2t, kmm, w1t);
    k_gemm2_mean<<<G2_BLOCKS, 256, 0, stream>>>(x, ga_w0, ga_b0, w1tGA,
                                                ga_b1, ga_w2, ga_b2, y1, part);
    k_fused24<<<NB / 4, 256, 0, stream>>>(y1, gac_w0, w1tGAC, gac_w2,
                                          gsc_w0, w1tGSC, gsc_w2,
                                          part, y_mean, yhat, yhat1, kmm);
    if (use_tbl) {
        k_gs_table<<<G2_BLOCKS + 24 * TBL_CAP, 256, 0, stream>>>(
            yhat1, gs_w0, gs_b0, w1tGS, gs_b1, gs_w2, gs_b2, xhat,
            eb, u2t, kmm, tbl);
        k_mc_tbl<<<NB, 256, 0, stream>>>(yhat, u2t, eb, kmm, tbl, lik);
    } else {
        k_gs_table<<<G2_BLOCKS, 256, 0, stream>>>(
            yhat1, gs_w0, gs_b0, w1tGS, gs_b1, gs_w2, gs_b2, xhat,
            eb, u2t, kmm, tbl);
        k_mc_direct<<<NB, 256, 0, stream>>>(yhat, u2t, eb, lik);
    }
}

// Round 8
// 140.210 us; speedup vs baseline: 1.0456x; 1.0456x over previous
//
#include <hip/hip_runtime.h>
#include <hip/hip_bf16.h>
#include <math.h>
#include <limits.h>

// Problem dims
constexpr int NB    = 4096;   // batch
constexpr int ROWS2 = NB * 12;            // 49152 rows for the 2->100->100->2 MLPs
constexpr int G2_BLOCKS = ROWS2 / 64;     // 768 (64 rows/block)
constexpr int TBL_CAP = 48;               // lattice slots per channel

// workspace layout (float offsets)
constexpr size_t WS_Y1    = 0;              // NB*24
constexpr size_t WS_YHAT  = 98304;          // NB*24
constexpr size_t WS_YHAT1 = 196608;         // NB*24
constexpr size_t WS_YM    = 294912;         // 24
constexpr size_t WS_U2T   = 294936;         // 24*256 (transposed: [c][m])
constexpr size_t WS_EB    = 301080;         // 24*58 precomputed prior params
constexpr size_t WS_KMM   = 302472;         // 48 ints (kmin[24], kmax[24])
constexpr size_t WS_PART  = 302520;         // 768*24 per-block mean partials
constexpr size_t WS_W1T   = 320952;         // 4 x [100][128] transposed w1 (51200)
constexpr size_t WS_TBL   = 372152;         // 24*48*256 table of log(pdf+1e-9)
constexpr size_t WS_END   = WS_TBL + 24 * TBL_CAP * 256;   // 667064 floats (~2.67 MB)

constexpr float STEP_ODD = 0.8660254037844386f;   // sqrt(3)/2
constexpr float INV_ODD  = 1.1547005383792517f;   // 2/sqrt(3)

__device__ __forceinline__ float lrelu(float x) { return x >= 0.f ? x : 0.01f * x; }
__device__ __forceinline__ float rcp_fast(float x) { return __builtin_amdgcn_rcpf(x); }

__device__ __forceinline__ float tanh_fast(float x) {
    float xx = fminf(fmaxf(x, -15.f), 15.f);
    float e = __expf(xx + xx);
    return fmaf(-2.f, rcp_fast(e + 1.f), 1.f);
}
__device__ __forceinline__ float splus(float x) {
    return fmaxf(x, 0.f) + __logf(1.f + __expf(-fabsf(x)));
}
__device__ __forceinline__ float splus_precise(float x) {
    return fmaxf(x, 0.f) + log1pf(expf(-fabsf(x)));
}

__device__ __forceinline__ void fma4(float4& a, float h, const float4& w) {
    a.x = fmaf(h, w.x, a.x); a.y = fmaf(h, w.y, a.y);
    a.z = fmaf(h, w.z, a.z); a.w = fmaf(h, w.w, a.w);
}

// exact A2 hex lattice nearest-point quantizer; matches jnp.round (rint = RNE)
__device__ __forceinline__ void hexq(float p0, float p1, float& q0, float& q1) {
    const float S3 = 1.7320508075688772f;
    const float H3 = 0.8660254037844386f;
    float c00 = rintf(p0);
    float c01 = rintf(p1 / S3) * S3;
    float c10 = rintf(p0 - 0.5f) + 0.5f;
    float c11 = rintf((p1 - H3) / S3) * S3 + H3;
    float d0 = (p0 - c00) * (p0 - c00) + (p1 - c01) * (p1 - c01);
    float d1 = (p0 - c10) * (p0 - c10) + (p1 - c11) * (p1 - c11);
    bool take0 = d0 <= d1;
    q0 = take0 ? c00 : c10;
    q1 = take0 ? c01 : c11;
}

// per-channel prior chain: log(pdf + 1e-9) at point p, params P (58 floats)
__device__ __forceinline__ float logpdf_ch(const float* __restrict__ P, float p) {
    float w00 = P[0], w01 = P[1], w02 = P[2];
    float z0 = fmaf(w00, p, P[3]);
    float z1 = fmaf(w01, p, P[4]);
    float z2 = fmaf(w02, p, P[5]);
    float a0 = P[6], a1 = P[7], a2 = P[8];
    float e0 = tanh_fast(z0), e1 = tanh_fast(z1), e2 = tanh_fast(z2);
    float h0 = fmaf(a0, e0, z0), h1 = fmaf(a1, e1, z1), h2 = fmaf(a2, e2, z2);
    float t0 = w00 * fmaf(a0, fmaf(-e0, e0, 1.f), 1.f);
    float t1 = w01 * fmaf(a1, fmaf(-e1, e1, 1.f), 1.f);
    float t2 = w02 * fmaf(a2, fmaf(-e2, e2, 1.f), 1.f);

#define EB_LAYER(O)                                                            \
    {                                                                          \
        float z0n = fmaf(P[O+0], h0, fmaf(P[O+1], h1, fmaf(P[O+2], h2, P[O+9])));  \
        float z1n = fmaf(P[O+3], h0, fmaf(P[O+4], h1, fmaf(P[O+5], h2, P[O+10]))); \
        float z2n = fmaf(P[O+6], h0, fmaf(P[O+7], h1, fmaf(P[O+8], h2, P[O+11]))); \
        float s0 = fmaf(P[O+0], t0, fmaf(P[O+1], t1, P[O+2] * t2));            \
        float s1 = fmaf(P[O+3], t0, fmaf(P[O+4], t1, P[O+5] * t2));            \
        float s2 = fmaf(P[O+6], t0, fmaf(P[O+7], t1, P[O+8] * t2));            \
        float g0 = P[O+12], g1 = P[O+13], g2 = P[O+14];                        \
        float q0 = tanh_fast(z0n), q1 = tanh_fast(z1n), q2 = tanh_fast(z2n);   \
        h0 = fmaf(g0, q0, z0n); h1 = fmaf(g1, q1, z1n); h2 = fmaf(g2, q2, z2n); \
        t0 = s0 * fmaf(g0, fmaf(-q0, q0, 1.f), 1.f);                           \
        t1 = s1 * fmaf(g1, fmaf(-q1, q1, 1.f), 1.f);                           \
        t2 = s2 * fmaf(g2, fmaf(-q2, q2, 1.f), 1.f);                           \
    }
    EB_LAYER(9)
    EB_LAYER(24)
    EB_LAYER(39)
#undef EB_LAYER

    float L = fmaf(P[54], h0, fmaf(P[55], h1, fmaf(P[56], h2, P[57])));
    float T = fmaf(P[54], t0, fmaf(P[55], t1, P[56] * t2));
    float Lc = fminf(fmaxf(L, -30.f), 30.f);
    float sg = rcp_fast(1.f + __expf(-Lc));
    float pdf = sg * (1.f - sg) * T;
    return __logf(pdf + 1e-9f);
}

// ---------------------------------------------------------------------------
// K0: block 0: prior params + u2^T + kmm init.
//     blocks 1..200: transpose the four 100x100 W1 matrices into [100][128]
// ---------------------------------------------------------------------------
__global__ __launch_bounds__(256) void k_prep(
    const float* __restrict__ H0p, const float* __restrict__ H1p,
    const float* __restrict__ H2p, const float* __restrict__ H3p,
    const float* __restrict__ H4p,
    const float* __restrict__ b0p, const float* __restrict__ b1p,
    const float* __restrict__ b2p, const float* __restrict__ b3p,
    const float* __restrict__ b4p,
    const float* __restrict__ a0p, const float* __restrict__ a1p,
    const float* __restrict__ a2p, const float* __restrict__ a3p,
    const float* __restrict__ u,
    const float* __restrict__ w1ga, const float* __restrict__ w1gac,
    const float* __restrict__ w1gsc, const float* __restrict__ w1gs,
    float* __restrict__ eb, float* __restrict__ u2t,
    int* __restrict__ kmm, float* __restrict__ w1t)
{
    int tid = threadIdx.x;
    if (blockIdx.x > 0) {
        int t = blockIdx.x - 1;             // 0..199
        int m = t / 50;
        int o = (t % 50) * 256 + tid;       // 0..12799
        int k = o >> 7, i = o & 127;
        const float* src = (m == 0) ? w1ga : (m == 1) ? w1gac
                         : (m == 2) ? w1gsc : w1gs;
        w1t[m * 12800 + o] = (i < 100) ? src[i * 100 + k] : 0.f;
        return;
    }
    if (tid < 24) {
        int c = tid;
        float* P = eb + c * 58;
        for (int j = 0; j < 3; ++j) P[j]      = splus_precise(H0p[c*3+j]);
        for (int j = 0; j < 3; ++j) P[3+j]    = b0p[c*3+j];
        for (int j = 0; j < 3; ++j) P[6+j]    = tanhf(a0p[c*3+j]);
        for (int j = 0; j < 9; ++j) P[9+j]    = splus_precise(H1p[c*9+j]);
        for (int j = 0; j < 3; ++j) P[18+j]   = b1p[c*3+j];
        for (int j = 0; j < 3; ++j) P[21+j]   = tanhf(a1p[c*3+j]);
        for (int j = 0; j < 9; ++j) P[24+j]   = splus_precise(H2p[c*9+j]);
        for (int j = 0; j < 3; ++j) P[33+j]   = b2p[c*3+j];
        for (int j = 0; j < 3; ++j) P[36+j]   = tanhf(a2p[c*3+j]);
        for (int j = 0; j < 9; ++j) P[39+j]   = splus_precise(H3p[c*9+j]);
        for (int j = 0; j < 3; ++j) P[48+j]   = b3p[c*3+j];
        for (int j = 0; j < 3; ++j) P[51+j]   = tanhf(a3p[c*3+j]);
        for (int j = 0; j < 3; ++j) P[54+j]   = splus_precise(H4p[c*3+j]);
        P[57] = b4p[c];
        kmm[tid]      = INT_MAX;
        kmm[24 + tid] = INT_MIN;
    }
    int m = tid;
    if (m < 256) {
        for (int j = 0; j < 12; ++j) {
            float a  = u[m*24 + 2*j];
            float bb = u[m*24 + 2*j + 1];
            float p0 = fmaf(0.5f, bb, a);
            float p1 = 0.8660254037844386f * bb;
            float q0, q1; hexq(p0, p1, q0, q1);
            u2t[(2*j)   * 256 + m] = p0 - q0;
            u2t[(2*j+1) * 256 + m] = p1 - q1;
        }
    }
}

// ---------------------------------------------------------------------------
// gemm2 body: 2 -> 100 (lrelu) -> 100 (lrelu) -> 2, register-tiled, weights
// streamed from L2 (pre-transposed w1t [100][128]); only h0^T in LDS.
// ---------------------------------------------------------------------------
template <int MEAN>
__device__ __forceinline__ void gemm2_body(
    int bid,
    const float* __restrict__ in,
    const float* __restrict__ w0, const float* __restrict__ b0,
    const float* __restrict__ w1t,
    const float* __restrict__ b1, const float* __restrict__ w2,
    const float* __restrict__ b2,
    float* __restrict__ out, float* __restrict__ partial)
{
    __shared__ alignas(16) float shT[100 * 64];   // h0T [k][row]; reused as red
    __shared__ float S[64][2];

    int tid = threadIdx.x;
    int row0 = bid * 64;

    int lrow = tid & 63, jg = tid >> 6;
    float2 xv = ((const float2*)in)[row0 + lrow];
#pragma unroll
    for (int jj = 0; jj < 25; ++jj) {
        int j = jg * 25 + jj;
        shT[j * 64 + lrow] =
            lrelu(fmaf(w0[2*j], xv.x, fmaf(w0[2*j+1], xv.y, b0[j])));
    }

    int lane = tid & 63, wv = tid >> 6;
    int ct = lane & 31;                 // col group: cols 4ct..4ct+3 of 128
    int rt = wv * 2 + (lane >> 5);      // row group: rows 8rt..8rt+7
    bool cvalid = (4 * ct < 100);
    float4 zero4 = make_float4(0.f, 0.f, 0.f, 0.f);
    float4 b14 = cvalid ? *(const float4*)(b1 + 4*ct) : zero4;
    float4 w20 = cvalid ? *(const float4*)(w2 + 4*ct) : zero4;
    float4 w21 = cvalid ? *(const float4*)(w2 + 100 + 4*ct) : zero4;
    __syncthreads();

    float4 acc[8];
#pragma unroll
    for (int r = 0; r < 8; ++r) acc[r] = zero4;
    const float4* wg  = (const float4*)w1t + ct;   // +32 float4 per k
    const float4* hT4 = (const float4*)shT;        // [100][16]
#pragma unroll 4
    for (int k = 0; k < 100; ++k) {
        float4 w4 = wg[k * 32];
        float4 ha = hT4[k * 16 + rt * 2];
        float4 hb = hT4[k * 16 + rt * 2 + 1];
        fma4(acc[0], ha.x, w4); fma4(acc[1], ha.y, w4);
        fma4(acc[2], ha.z, w4); fma4(acc[3], ha.w, w4);
        fma4(acc[4], hb.x, w4); fma4(acc[5], hb.y, w4);
        fma4(acc[6], hb.z, w4); fma4(acc[7], hb.w, w4);
    }
    __syncthreads();          // h reads done; reuse shT as reduction pad

    float* red = shT;         // [64][2][32]
#pragma unroll
    for (int r = 0; r < 8; ++r) {
        float a0 = lrelu(acc[r].x + b14.x);
        float a1 = lrelu(acc[r].y + b14.y);
        float a2 = lrelu(acc[r].z + b14.z);
        float a3 = lrelu(acc[r].w + b14.w);
        float y0 = fmaf(a0, w20.x, fmaf(a1, w20.y, fmaf(a2, w20.z, a3 * w20.w)));
        float y1 = fmaf(a0, w21.x, fmaf(a1, w21.y, fmaf(a2, w21.z, a3 * w21.w)));
        int row = rt * 8 + r;
        red[(row * 2) * 32 + ct]     = y0;
        red[(row * 2 + 1) * 32 + ct] = y1;
    }
    __syncthreads();
    if (tid < 128) {
        int row = tid >> 1, p = tid & 1;
        const float4* rp = (const float4*)&red[(row * 2 + p) * 32];
        float s = 0.f;
#pragma unroll
        for (int g = 0; g < 8; ++g) {
            float4 v = rp[g];
            s += (v.x + v.y) + (v.z + v.w);
        }
        float y = s + b2[p];
        out[(row0 + row) * 2 + p] = y;
        if (MEAN) S[row][p] = y;
    }
    if (MEAN) {
        __syncthreads();
        if (tid < 24) {
            int j = tid >> 1, par = tid & 1;
            int base = row0 % 12;
            int k0 = (j - base + 12) % 12;
            float s = 0.f;
            for (int k = k0; k < 64; k += 12) s += S[k][par];
            partial[bid * 24 + tid] = s;
        }
    }
}

__global__ __launch_bounds__(256, 4) void k_gemm2_mean(
    const float* __restrict__ in,
    const float* __restrict__ w0, const float* __restrict__ b0,
    const float* __restrict__ w1t,
    const float* __restrict__ b1, const float* __restrict__ w2,
    const float* __restrict__ b2,
    float* __restrict__ out, float* __restrict__ partial)
{
    gemm2_body<1>(blockIdx.x, in, w0, b0, w1t, b1, w2, b2, out, partial);
}

// ---------------------------------------------------------------------------
// K2: finish the EMA mean from 768 per-block partials (1 block, sub-us)
// ---------------------------------------------------------------------------
__global__ __launch_bounds__(256) void k_mean_final(
    const float* __restrict__ partial, const float* __restrict__ y_mean,
    float* __restrict__ ym)
{
    int tid = threadIdx.x;
    int c = tid >> 3, s = tid & 7;
    float v = 0.f;
    if (c < 24)
        for (int g = s; g < G2_BLOCKS; g += 8) v += partial[g * 24 + c];
    v += __shfl_xor(v, 1); v += __shfl_xor(v, 2); v += __shfl_xor(v, 4);
    if (c < 24 && s == 0)
        ym[c] = fmaf(0.05f, y_mean[c], 0.95f * (v * (1.0f / NB)));
}

// ---------------------------------------------------------------------------
// K3: FUSED coupled transforms. 8 rows/block, 512 blocks (2/CU, 8 waves/CU).
// Per pass: stage w0,w2 into LDS (coalesced); layer-0/2 read weights from
// LDS; layer-1 streams w1t coalesced from L2 (thread=(rg,i), 4 rows, 4 FMA
// per load, h0 read wave-uniform as b128). ym precomputed by k_mean_final.
// Pass A: yhat = hexq(gac(y1-ym)) + kmm.  Pass B: yhat1 = gsc(yhat) + ym.
// ---------------------------------------------------------------------------
__global__ __launch_bounds__(256, 4) void k_fused24(
    const float* __restrict__ y1,
    const float* __restrict__ w0A, const float* __restrict__ w1tA,
    const float* __restrict__ w2A,
    const float* __restrict__ w0B, const float* __restrict__ w1tB,
    const float* __restrict__ w2B,
    const float* __restrict__ ymg,
    float* __restrict__ yhat, float* __restrict__ yhat1,
    int* __restrict__ kmm)
{
    __shared__ float sw0[2400];
    __shared__ float sw2[2400];
    __shared__ float sX[8 * 25];
    __shared__ float sO[8 * 25];
    __shared__ alignas(16) float h0[100 * 8];   // [j][r]
    __shared__ float h1[100 * 8];               // [i][r]
    __shared__ float symL[24];
    __shared__ int kminL[24], kmaxL[24];

    int tid = threadIdx.x;
    int row0 = blockIdx.x * 8;

    if (tid < 24) {
        symL[tid] = ymg[tid];
        kminL[tid] = INT_MAX; kmaxL[tid] = INT_MIN;
    }
    __syncthreads();
    for (int e = tid; e < 192; e += 256) {
        int r = e / 24, c = e - r * 24;
        sX[r * 25 + c] = y1[row0 * 24 + e] - symL[c];
    }

    int ii = tid & 127, rg = tid >> 7;

    for (int pass = 0; pass < 2; ++pass) {
        const float* w0  = pass ? w0B  : w0A;
        const float* w1t = pass ? w1tB : w1tA;
        const float* w2  = pass ? w2B  : w2A;
        for (int t = tid; t < 2400; t += 256) {
            sw0[t] = w0[t];
            sw2[t] = w2[t];
        }
        __syncthreads();   // staging + sX ready

        // layer 0: h0[j][r], 800 outputs, weights from LDS
        for (int e = tid; e < 800; e += 256) {
            int j = e >> 3, r = e & 7;
            const float* wr = sw0 + j * 24;
            const float* xr = sX + r * 25;
            float a = 0.f, b = 0.f;
#pragma unroll
            for (int k = 0; k < 24; k += 2) {
                a = fmaf(wr[k],     xr[k],     a);
                b = fmaf(wr[k + 1], xr[k + 1], b);
            }
            h0[j * 8 + r] = splus(a + b);
        }
        __syncthreads();

        // layer 1: thread (rg, ii) -> z1[ii] for rows 4rg..4rg+3
        {
            float4 a = make_float4(0.f, 0.f, 0.f, 0.f);
            const float* wc = w1t + ii;
            const float4* h4 = (const float4*)h0 + rg;   // [j][2] float4
#pragma unroll 4
            for (int j = 0; j < 100; ++j) {
                float w = wc[j * 128];
                float4 h = h4[j * 2];
                a.x = fmaf(w, h.x, a.x); a.y = fmaf(w, h.y, a.y);
                a.z = fmaf(w, h.z, a.z); a.w = fmaf(w, h.w, a.w);
            }
            if (ii < 100) {
                h1[ii * 8 + rg * 4]     = splus(a.x);
                h1[ii * 8 + rg * 4 + 1] = splus(a.y);
                h1[ii * 8 + rg * 4 + 2] = splus(a.z);
                h1[ii * 8 + rg * 4 + 3] = splus(a.w);
            }
        }
        __syncthreads();

        // layer 2: 192 outputs, weights from LDS
        if (tid < 192) {
            int c = tid >> 3, r = tid & 7;
            const float* w2r = sw2 + c * 100;
            float s = 0.f, s2 = 0.f;
#pragma unroll 4
            for (int i = 0; i < 100; i += 2) {
                s  = fmaf(w2r[i],     h1[i * 8 + r],       s);
                s2 = fmaf(w2r[i + 1], h1[(i + 1) * 8 + r], s2);
            }
            float v = s + s2;
            if (pass == 0) sO[r * 25 + c] = v;
            else yhat1[(row0 + r) * 24 + c] = v + symL[c];
        }

        if (pass == 0) {
            __syncthreads();
            if (tid < 96) {
                int pr = tid >> 3, r = tid & 7;
                float v0 = sO[r * 25 + 2*pr], v1 = sO[r * 25 + 2*pr + 1];
                float q0, q1; hexq(v0, v1, q0, q1);
                yhat[(row0 + r) * 24 + 2*pr]     = q0;
                yhat[(row0 + r) * 24 + 2*pr + 1] = q1;
                sX[r * 25 + 2*pr]     = q0;       // pass-B input
                sX[r * 25 + 2*pr + 1] = q1;
                int k0 = (int)rintf(q0 * 2.0f);
                int k1 = (int)rintf(q1 * INV_ODD);
                atomicMin(&kminL[2*pr], k0);     atomicMax(&kmaxL[2*pr], k0);
                atomicMin(&kminL[2*pr + 1], k1); atomicMax(&kmaxL[2*pr + 1], k1);
            }
        }
    }
    __syncthreads();
    if (tid < 24) {
        atomicMin(&kmm[tid], kminL[tid]);
        atomicMax(&kmm[24 + tid], kmaxL[tid]);
    }
}

// ---------------------------------------------------------------------------
// K4: merged dispatch: blocks [0,768) = gs GEMM (xhat), blocks [768,1920) =
// prior table build. Both depend only on k_fused24.
// ---------------------------------------------------------------------------
__global__ __launch_bounds__(256, 4) void k_gs_table(
    const float* __restrict__ yhat1,
    const float* __restrict__ w0, const float* __restrict__ b0,
    const float* __restrict__ w1t,
    const float* __restrict__ b1, const float* __restrict__ w2,
    const float* __restrict__ b2, float* __restrict__ xhat,
    const float* __restrict__ eb, const float* __restrict__ u2t,
    const int* __restrict__ kmm, float* __restrict__ tbl)
{
    if (blockIdx.x < (unsigned)G2_BLOCKS) {
        gemm2_body<0>(blockIdx.x, yhat1, w0, b0, w1t, b1, w2, b2, xhat, nullptr);
    } else {
        int cv = blockIdx.x - G2_BLOCKS;
        int c = cv / TBL_CAP, v = cv - c * TBL_CAP;
        int m = threadIdx.x;
        float step = (c & 1) ? STEP_ODD : 0.5f;
        float val = (float)(kmm[c] + v) * step;
        float p = val + u2t[c * 256 + m];
        tbl[cv * 256 + m] = logpdf_ch(eb + c * 58, p);
    }
}

// ---------------------------------------------------------------------------
// K5: MC likelihood via table gather; shuffle-based logsumexp.
// ---------------------------------------------------------------------------
__global__ __launch_bounds__(256) void k_mc_tbl(
    const float* __restrict__ yhat, const float* __restrict__ u2t,
    const float* __restrict__ eb, const int* __restrict__ kmm,
    const float* __restrict__ tbl, float* __restrict__ lik)
{
    __shared__ float redm[4], reds[4];
    int tid = threadIdx.x;
    int wv = tid >> 6;
    int b = blockIdx.x;

    float y[24];
    const float4* yr = (const float4*)(yhat + b * 24);
#pragma unroll
    for (int k4 = 0; k4 < 6; ++k4) {
        float4 t = yr[k4];
        y[4*k4] = t.x; y[4*k4+1] = t.y; y[4*k4+2] = t.z; y[4*k4+3] = t.w;
    }

    float lp = 0.f;
    unsigned miss = 0;
#pragma unroll
    for (int c = 0; c < 24; ++c) {
        float inv = (c & 1) ? INV_ODD : 2.0f;
        int k = (int)rintf(y[c] * inv);
        int idx = k - kmm[c];
        if (idx >= 0 && idx < TBL_CAP)
            lp += tbl[(c * TBL_CAP + idx) * 256 + tid];
        else
            miss |= (1u << c);
    }
    while (miss) {   // rare fallback: channel exceeded TBL_CAP lattice slots
        int c = __ffs(miss) - 1;
        miss &= miss - 1;
        lp += logpdf_ch(eb + c * 58, y[c] + u2t[c * 256 + tid]);
    }

    float m = lp;
#pragma unroll
    for (int off = 1; off < 64; off <<= 1) m = fmaxf(m, __shfl_xor(m, off));
    if ((tid & 63) == 0) redm[wv] = m;
    __syncthreads();
    float mx = fmaxf(fmaxf(redm[0], redm[1]), fmaxf(redm[2], redm[3]));
    float e = __expf(lp - mx);
#pragma unroll
    for (int off = 1; off < 64; off <<= 1) e += __shfl_xor(e, off);
    if ((tid & 63) == 0) reds[wv] = e;
    __syncthreads();
    if (tid == 0)
        lik[b] = mx + __logf(reds[0] + reds[1] + reds[2] + reds[3])
               - 7.271269879190247f;  // -log(NMC) + LOG_VOL
}

// ---------------------------------------------------------------------------
// K5 fallback (ws too small): direct MC
// ---------------------------------------------------------------------------
__global__ __launch_bounds__(256) void k_mc_direct(
    const float* __restrict__ yhat, const float* __restrict__ u2t,
    const float* __restrict__ eb, float* __restrict__ lik)
{
    __shared__ alignas(16) float sU[24 * 256];
    __shared__ float redm[4], reds[4];
    int tid = threadIdx.x;
    int wv = tid >> 6;
    int b = blockIdx.x;
    for (int i = tid; i < 1536; i += 256)
        ((float4*)sU)[i] = ((const float4*)u2t)[i];
    __syncthreads();

    float lp = 0.f;
    for (int c = 0; c < 24; ++c)
        lp += logpdf_ch(eb + c * 58, yhat[b * 24 + c] + sU[c * 256 + tid]);

    float m = lp;
#pragma unroll
    for (int off = 1; off < 64; off <<= 1) m = fmaxf(m, __shfl_xor(m, off));
    if ((tid & 63) == 0) redm[wv] = m;
    __syncthreads();
    float mx = fmaxf(fmaxf(redm[0], redm[1]), fmaxf(redm[2], redm[3]));
    float e = __expf(lp - mx);
#pragma unroll
    for (int off = 1; off < 64; off <<= 1) e += __shfl_xor(e, off);
    if ((tid & 63) == 0) reds[wv] = e;
    __syncthreads();
    if (tid == 0)
        lik[b] = mx + __logf(reds[0] + reds[1] + reds[2] + reds[3])
               - 7.271269879190247f;
}

// ---------------------------------------------------------------------------
extern "C" void kernel_launch(void* const* d_in, const int* in_sizes, int n_in,
                              void* d_out, int out_size, void* d_ws, size_t ws_size,
                              hipStream_t stream)
{
    (void)in_sizes; (void)n_in; (void)out_size;
    const float* x      = (const float*)d_in[0];
    const float* y_mean = (const float*)d_in[1];
    const float* u      = (const float*)d_in[2];
    const float* ga_w0  = (const float*)d_in[3];
    const float* ga_b0  = (const float*)d_in[4];
    const float* ga_w1  = (const float*)d_in[5];
    const float* ga_b1  = (const float*)d_in[6];
    const float* ga_w2  = (const float*)d_in[7];
    const float* ga_b2  = (const float*)d_in[8];
    const float* gs_w0  = (const float*)d_in[9];
    const float* gs_b0  = (const float*)d_in[10];
    const float* gs_w1  = (const float*)d_in[11];
    const float* gs_b1  = (const float*)d_in[12];
    const float* gs_w2  = (const float*)d_in[13];
    const float* gs_b2  = (const float*)d_in[14];
    const float* gac_w0 = (const float*)d_in[15];
    const float* gac_w1 = (const float*)d_in[16];
    const float* gac_w2 = (const float*)d_in[17];
    const float* gsc_w0 = (const float*)d_in[18];
    const float* gsc_w1 = (const float*)d_in[19];
    const float* gsc_w2 = (const float*)d_in[20];
    const float* eb_H0  = (const float*)d_in[21];
    const float* eb_H1  = (const float*)d_in[22];
    const float* eb_H2  = (const float*)d_in[23];
    const float* eb_H3  = (const float*)d_in[24];
    const float* eb_H4  = (const float*)d_in[25];
    const float* eb_b0  = (const float*)d_in[26];
    const float* eb_b1  = (const float*)d_in[27];
    const float* eb_b2  = (const float*)d_in[28];
    const float* eb_b3  = (const float*)d_in[29];
    const float* eb_b4  = (const float*)d_in[30];
    const float* eb_a0  = (const float*)d_in[31];
    const float* eb_a1  = (const float*)d_in[32];
    const float* eb_a2  = (const float*)d_in[33];
    const float* eb_a3  = (const float*)d_in[34];

    float* ws    = (float*)d_ws;
    float* y1    = ws + WS_Y1;
    float* yhat  = ws + WS_YHAT;
    float* yhat1 = ws + WS_YHAT1;
    float* ym    = ws + WS_YM;
    float* u2t   = ws + WS_U2T;
    float* eb    = ws + WS_EB;
    int*   kmm   = (int*)(ws + WS_KMM);
    float* part  = ws + WS_PART;
    float* w1t   = ws + WS_W1T;
    float* tbl   = ws + WS_TBL;
    float* xhat  = (float*)d_out;
    float* lik   = (float*)d_out + 98304;

    float* w1tGA  = w1t;
    float* w1tGAC = w1t + 12800;
    float* w1tGSC = w1t + 25600;
    float* w1tGS  = w1t + 38400;

    bool use_tbl = ws_size >= WS_END * sizeof(float);

    k_prep<<<201, 256, 0, stream>>>(eb_H0, eb_H1, eb_H2, eb_H3, eb_H4,
                                    eb_b0, eb_b1, eb_b2, eb_b3, eb_b4,
                                    eb_a0, eb_a1, eb_a2, eb_a3, u,
                                    ga_w1, gac_w1, gsc_w1, gs_w1,
                                    eb, u2t, kmm, w1t);
    k_gemm2_mean<<<G2_BLOCKS, 256, 0, stream>>>(x, ga_w0, ga_b0, w1tGA,
                                                ga_b1, ga_w2, ga_b2, y1, part);
    k_mean_final<<<1, 256, 0, stream>>>(part, y_mean, ym);
    k_fused24<<<NB / 8, 256, 0, stream>>>(y1, gac_w0, w1tGAC, gac_w2,
                                          gsc_w0, w1tGSC, gsc_w2,
                                          ym, yhat, yhat1, kmm);
    if (use_tbl) {
        k_gs_table<<<G2_BLOCKS + 24 * TBL_CAP, 256, 0, stream>>>(
            yhat1, gs_w0, gs_b0, w1tGS, gs_b1, gs_w2, gs_b2, xhat,
            eb, u2t, kmm, tbl);
        k_mc_tbl<<<NB, 256, 0, stream>>>(yhat, u2t, eb, kmm, tbl, lik);
    } else {
        k_gs_table<<<G2_BLOCKS, 256, 0, stream>>>(
            yhat1, gs_w0, gs_b0, w1tGS, gs_b1, gs_w2, gs_b2, xhat,
            eb, u2t, kmm, tbl);
        k_mc_direct<<<NB, 256, 0, stream>>>(yhat, u2t, eb, lik);
    }
}

// Round 9
// 131.868 us; speedup vs baseline: 1.1118x; 1.0633x over previous
//
#include <hip/hip_runtime.h>
#include <hip/hip_bf16.h>
#include <math.h>
#include <limits.h>

// Problem dims
constexpr int NB    = 4096;   // batch
constexpr int ROWS2 = NB * 12;            // 49152 rows for the 2->100->100->2 MLPs
constexpr int G2_BLOCKS = ROWS2 / 64;     // 768 (64 rows/block)
constexpr int TBL_CAP = 64;               // lattice slots per channel (fixed range)
constexpr int KBASE   = -32;              // fixed kmin for all channels

// workspace layout (float offsets)
constexpr size_t WS_Y1    = 0;              // NB*24
constexpr size_t WS_YHAT  = 98304;          // NB*24
constexpr size_t WS_YHAT1 = 196608;         // NB*24
constexpr size_t WS_YM    = 294912;         // 24
constexpr size_t WS_U2T   = 294936;         // 24*256 (transposed: [c][m])
constexpr size_t WS_EB    = 301080;         // 24*58 precomputed prior params
constexpr size_t WS_PART  = 302472;         // 768*24 per-block mean partials
constexpr size_t WS_W1T   = 320904;         // 4 x [100][128] transposed w1 (51200)
constexpr size_t WS_TBL   = 372104;         // 24*64*256 table of log(pdf+1e-9)
constexpr size_t WS_END   = WS_TBL + 24 * TBL_CAP * 256;   // 765320 floats (~3.06 MB)

constexpr float STEP_ODD = 0.8660254037844386f;   // sqrt(3)/2
constexpr float INV_ODD  = 1.1547005383792517f;   // 2/sqrt(3)

__device__ __forceinline__ float lrelu(float x) { return x >= 0.f ? x : 0.01f * x; }
__device__ __forceinline__ float rcp_fast(float x) { return __builtin_amdgcn_rcpf(x); }

__device__ __forceinline__ float tanh_fast(float x) {
    float xx = fminf(fmaxf(x, -15.f), 15.f);
    float e = __expf(xx + xx);
    return fmaf(-2.f, rcp_fast(e + 1.f), 1.f);
}
__device__ __forceinline__ float splus(float x) {
    return fmaxf(x, 0.f) + __logf(1.f + __expf(-fabsf(x)));
}
__device__ __forceinline__ float splus_precise(float x) {
    return fmaxf(x, 0.f) + log1pf(expf(-fabsf(x)));
}

__device__ __forceinline__ void fma4(float4& a, float h, const float4& w) {
    a.x = fmaf(h, w.x, a.x); a.y = fmaf(h, w.y, a.y);
    a.z = fmaf(h, w.z, a.z); a.w = fmaf(h, w.w, a.w);
}

// exact A2 hex lattice nearest-point quantizer; matches jnp.round (rint = RNE)
__device__ __forceinline__ void hexq(float p0, float p1, float& q0, float& q1) {
    const float S3 = 1.7320508075688772f;
    const float H3 = 0.8660254037844386f;
    float c00 = rintf(p0);
    float c01 = rintf(p1 / S3) * S3;
    float c10 = rintf(p0 - 0.5f) + 0.5f;
    float c11 = rintf((p1 - H3) / S3) * S3 + H3;
    float d0 = (p0 - c00) * (p0 - c00) + (p1 - c01) * (p1 - c01);
    float d1 = (p0 - c10) * (p0 - c10) + (p1 - c11) * (p1 - c11);
    bool take0 = d0 <= d1;
    q0 = take0 ? c00 : c10;
    q1 = take0 ? c01 : c11;
}

// per-channel prior chain: log(pdf + 1e-9) at point p, params P (58 floats)
__device__ __forceinline__ float logpdf_ch(const float* __restrict__ P, float p) {
    float w00 = P[0], w01 = P[1], w02 = P[2];
    float z0 = fmaf(w00, p, P[3]);
    float z1 = fmaf(w01, p, P[4]);
    float z2 = fmaf(w02, p, P[5]);
    float a0 = P[6], a1 = P[7], a2 = P[8];
    float e0 = tanh_fast(z0), e1 = tanh_fast(z1), e2 = tanh_fast(z2);
    float h0 = fmaf(a0, e0, z0), h1 = fmaf(a1, e1, z1), h2 = fmaf(a2, e2, z2);
    float t0 = w00 * fmaf(a0, fmaf(-e0, e0, 1.f), 1.f);
    float t1 = w01 * fmaf(a1, fmaf(-e1, e1, 1.f), 1.f);
    float t2 = w02 * fmaf(a2, fmaf(-e2, e2, 1.f), 1.f);

#define EB_LAYER(O)                                                            \
    {                                                                          \
        float z0n = fmaf(P[O+0], h0, fmaf(P[O+1], h1, fmaf(P[O+2], h2, P[O+9])));  \
        float z1n = fmaf(P[O+3], h0, fmaf(P[O+4], h1, fmaf(P[O+5], h2, P[O+10]))); \
        float z2n = fmaf(P[O+6], h0, fmaf(P[O+7], h1, fmaf(P[O+8], h2, P[O+11]))); \
        float s0 = fmaf(P[O+0], t0, fmaf(P[O+1], t1, P[O+2] * t2));            \
        float s1 = fmaf(P[O+3], t0, fmaf(P[O+4], t1, P[O+5] * t2));            \
        float s2 = fmaf(P[O+6], t0, fmaf(P[O+7], t1, P[O+8] * t2));            \
        float g0 = P[O+12], g1 = P[O+13], g2 = P[O+14];                        \
        float q0 = tanh_fast(z0n), q1 = tanh_fast(z1n), q2 = tanh_fast(z2n);   \
        h0 = fmaf(g0, q0, z0n); h1 = fmaf(g1, q1, z1n); h2 = fmaf(g2, q2, z2n); \
        t0 = s0 * fmaf(g0, fmaf(-q0, q0, 1.f), 1.f);                           \
        t1 = s1 * fmaf(g1, fmaf(-q1, q1, 1.f), 1.f);                           \
        t2 = s2 * fmaf(g2, fmaf(-q2, q2, 1.f), 1.f);                           \
    }
    EB_LAYER(9)
    EB_LAYER(24)
    EB_LAYER(39)
#undef EB_LAYER

    float L = fmaf(P[54], h0, fmaf(P[55], h1, fmaf(P[56], h2, P[57])));
    float T = fmaf(P[54], t0, fmaf(P[55], t1, P[56] * t2));
    float Lc = fminf(fmaxf(L, -30.f), 30.f);
    float sg = rcp_fast(1.f + __expf(-Lc));
    float pdf = sg * (1.f - sg) * T;
    return __logf(pdf + 1e-9f);
}

// ---------------------------------------------------------------------------
// K0: block 0: prior params + u2^T.
//     blocks 1..200: transpose the four 100x100 W1 matrices into [100][128]
// ---------------------------------------------------------------------------
__global__ __launch_bounds__(256) void k_prep(
    const float* __restrict__ H0p, const float* __restrict__ H1p,
    const float* __restrict__ H2p, const float* __restrict__ H3p,
    const float* __restrict__ H4p,
    const float* __restrict__ b0p, const float* __restrict__ b1p,
    const float* __restrict__ b2p, const float* __restrict__ b3p,
    const float* __restrict__ b4p,
    const float* __restrict__ a0p, const float* __restrict__ a1p,
    const float* __restrict__ a2p, const float* __restrict__ a3p,
    const float* __restrict__ u,
    const float* __restrict__ w1ga, const float* __restrict__ w1gac,
    const float* __restrict__ w1gsc, const float* __restrict__ w1gs,
    float* __restrict__ eb, float* __restrict__ u2t,
    float* __restrict__ w1t)
{
    int tid = threadIdx.x;
    if (blockIdx.x > 0) {
        int t = blockIdx.x - 1;             // 0..199
        int m = t / 50;
        int o = (t % 50) * 256 + tid;       // 0..12799
        int k = o >> 7, i = o & 127;
        const float* src = (m == 0) ? w1ga : (m == 1) ? w1gac
                         : (m == 2) ? w1gsc : w1gs;
        w1t[m * 12800 + o] = (i < 100) ? src[i * 100 + k] : 0.f;
        return;
    }
    if (tid < 24) {
        int c = tid;
        float* P = eb + c * 58;
        for (int j = 0; j < 3; ++j) P[j]      = splus_precise(H0p[c*3+j]);
        for (int j = 0; j < 3; ++j) P[3+j]    = b0p[c*3+j];
        for (int j = 0; j < 3; ++j) P[6+j]    = tanhf(a0p[c*3+j]);
        for (int j = 0; j < 9; ++j) P[9+j]    = splus_precise(H1p[c*9+j]);
        for (int j = 0; j < 3; ++j) P[18+j]   = b1p[c*3+j];
        for (int j = 0; j < 3; ++j) P[21+j]   = tanhf(a1p[c*3+j]);
        for (int j = 0; j < 9; ++j) P[24+j]   = splus_precise(H2p[c*9+j]);
        for (int j = 0; j < 3; ++j) P[33+j]   = b2p[c*3+j];
        for (int j = 0; j < 3; ++j) P[36+j]   = tanhf(a2p[c*3+j]);
        for (int j = 0; j < 9; ++j) P[39+j]   = splus_precise(H3p[c*9+j]);
        for (int j = 0; j < 3; ++j) P[48+j]   = b3p[c*3+j];
        for (int j = 0; j < 3; ++j) P[51+j]   = tanhf(a3p[c*3+j]);
        for (int j = 0; j < 3; ++j) P[54+j]   = splus_precise(H4p[c*3+j]);
        P[57] = b4p[c];
    }
    int m = tid;
    if (m < 256) {
        for (int j = 0; j < 12; ++j) {
            float a  = u[m*24 + 2*j];
            float bb = u[m*24 + 2*j + 1];
            float p0 = fmaf(0.5f, bb, a);
            float p1 = 0.8660254037844386f * bb;
            float q0, q1; hexq(p0, p1, q0, q1);
            u2t[(2*j)   * 256 + m] = p0 - q0;
            u2t[(2*j+1) * 256 + m] = p1 - q1;
        }
    }
}

// ---------------------------------------------------------------------------
// gemm2 body: 2 -> 100 (lrelu) -> 100 (lrelu) -> 2, register-tiled, weights
// streamed from L2 (pre-transposed w1t [100][128]); only h0^T in LDS.
// ---------------------------------------------------------------------------
template <int MEAN>
__device__ __forceinline__ void gemm2_body(
    int bid,
    const float* __restrict__ in,
    const float* __restrict__ w0, const float* __restrict__ b0,
    const float* __restrict__ w1t,
    const float* __restrict__ b1, const float* __restrict__ w2,
    const float* __restrict__ b2,
    float* __restrict__ out, float* __restrict__ partial)
{
    __shared__ alignas(16) float shT[100 * 64];   // h0T [k][row]; reused as red
    __shared__ float S[64][2];

    int tid = threadIdx.x;
    int row0 = bid * 64;

    int lrow = tid & 63, jg = tid >> 6;
    float2 xv = ((const float2*)in)[row0 + lrow];
#pragma unroll
    for (int jj = 0; jj < 25; ++jj) {
        int j = jg * 25 + jj;
        shT[j * 64 + lrow] =
            lrelu(fmaf(w0[2*j], xv.x, fmaf(w0[2*j+1], xv.y, b0[j])));
    }

    int lane = tid & 63, wv = tid >> 6;
    int ct = lane & 31;                 // col group: cols 4ct..4ct+3 of 128
    int rt = wv * 2 + (lane >> 5);      // row group: rows 8rt..8rt+7
    bool cvalid = (4 * ct < 100);
    float4 zero4 = make_float4(0.f, 0.f, 0.f, 0.f);
    float4 b14 = cvalid ? *(const float4*)(b1 + 4*ct) : zero4;
    float4 w20 = cvalid ? *(const float4*)(w2 + 4*ct) : zero4;
    float4 w21 = cvalid ? *(const float4*)(w2 + 100 + 4*ct) : zero4;
    __syncthreads();

    float4 acc[8];
#pragma unroll
    for (int r = 0; r < 8; ++r) acc[r] = zero4;
    const float4* wg  = (const float4*)w1t + ct;   // +32 float4 per k
    const float4* hT4 = (const float4*)shT;        // [100][16]
#pragma unroll 4
    for (int k = 0; k < 100; ++k) {
        float4 w4 = wg[k * 32];
        float4 ha = hT4[k * 16 + rt * 2];
        float4 hb = hT4[k * 16 + rt * 2 + 1];
        fma4(acc[0], ha.x, w4); fma4(acc[1], ha.y, w4);
        fma4(acc[2], ha.z, w4); fma4(acc[3], ha.w, w4);
        fma4(acc[4], hb.x, w4); fma4(acc[5], hb.y, w4);
        fma4(acc[6], hb.z, w4); fma4(acc[7], hb.w, w4);
    }
    __syncthreads();          // h reads done; reuse shT as reduction pad

    float* red = shT;         // [64][2][32]
#pragma unroll
    for (int r = 0; r < 8; ++r) {
        float a0 = lrelu(acc[r].x + b14.x);
        float a1 = lrelu(acc[r].y + b14.y);
        float a2 = lrelu(acc[r].z + b14.z);
        float a3 = lrelu(acc[r].w + b14.w);
        float y0 = fmaf(a0, w20.x, fmaf(a1, w20.y, fmaf(a2, w20.z, a3 * w20.w)));
        float y1 = fmaf(a0, w21.x, fmaf(a1, w21.y, fmaf(a2, w21.z, a3 * w21.w)));
        int row = rt * 8 + r;
        red[(row * 2) * 32 + ct]     = y0;
        red[(row * 2 + 1) * 32 + ct] = y1;
    }
    __syncthreads();
    if (tid < 128) {
        int row = tid >> 1, p = tid & 1;
        const float4* rp = (const float4*)&red[(row * 2 + p) * 32];
        float s = 0.f;
#pragma unroll
        for (int g = 0; g < 8; ++g) {
            float4 v = rp[g];
            s += (v.x + v.y) + (v.z + v.w);
        }
        float y = s + b2[p];
        out[(row0 + row) * 2 + p] = y;
        if (MEAN) S[row][p] = y;
    }
    if (MEAN) {
        __syncthreads();
        if (tid < 24) {
            int j = tid >> 1, par = tid & 1;
            int base = row0 % 12;
            int k0 = (j - base + 12) % 12;
            float s = 0.f;
            for (int k = k0; k < 64; k += 12) s += S[k][par];
            partial[bid * 24 + tid] = s;
        }
    }
}

// ---------------------------------------------------------------------------
// K1: merged dispatch: blocks [0,768) = ga GEMM (y1 + mean partials),
// blocks [768, 768+1536) = prior table build (fixed range, needs only prep).
// ---------------------------------------------------------------------------
__global__ __launch_bounds__(256, 4) void k_ga_table(
    const float* __restrict__ in,
    const float* __restrict__ w0, const float* __restrict__ b0,
    const float* __restrict__ w1t,
    const float* __restrict__ b1, const float* __restrict__ w2,
    const float* __restrict__ b2,
    float* __restrict__ out, float* __restrict__ partial,
    const float* __restrict__ eb, const float* __restrict__ u2t,
    float* __restrict__ tbl)
{
    if (blockIdx.x < (unsigned)G2_BLOCKS) {
        gemm2_body<1>(blockIdx.x, in, w0, b0, w1t, b1, w2, b2, out, partial);
    } else {
        int cv = blockIdx.x - G2_BLOCKS;
        int c = cv >> 6, v = cv & 63;
        int m = threadIdx.x;
        float step = (c & 1) ? STEP_ODD : 0.5f;
        float val = (float)(KBASE + v) * step;
        float p = val + u2t[c * 256 + m];
        tbl[cv * 256 + m] = logpdf_ch(eb + c * 58, p);
    }
}

// ---------------------------------------------------------------------------
// K2: finish the EMA mean from 768 per-block partials (1 block, sub-us)
// ---------------------------------------------------------------------------
__global__ __launch_bounds__(256) void k_mean_final(
    const float* __restrict__ partial, const float* __restrict__ y_mean,
    float* __restrict__ ym)
{
    int tid = threadIdx.x;
    int c = tid >> 3, s = tid & 7;
    float v = 0.f;
    if (c < 24)
        for (int g = s; g < G2_BLOCKS; g += 8) v += partial[g * 24 + c];
    v += __shfl_xor(v, 1); v += __shfl_xor(v, 2); v += __shfl_xor(v, 4);
    if (c < 24 && s == 0)
        ym[c] = fmaf(0.05f, y_mean[c], 0.95f * (v * (1.0f / NB)));
}

// ---------------------------------------------------------------------------
// K3: FUSED coupled transforms. 8 rows/block, 512 blocks (2/CU, 8 waves/CU).
// No kmm atomics (fixed table range). Pass A: yhat = hexq(gac(y1-ym)).
// Pass B: yhat1 = gsc(yhat) + ym.
// ---------------------------------------------------------------------------
__global__ __launch_bounds__(256, 4) void k_fused24(
    const float* __restrict__ y1,
    const float* __restrict__ w0A, const float* __restrict__ w1tA,
    const float* __restrict__ w2A,
    const float* __restrict__ w0B, const float* __restrict__ w1tB,
    const float* __restrict__ w2B,
    const float* __restrict__ ymg,
    float* __restrict__ yhat, float* __restrict__ yhat1)
{
    __shared__ float sw0[2400];
    __shared__ float sw2[2400];
    __shared__ float sX[8 * 25];
    __shared__ float sO[8 * 25];
    __shared__ alignas(16) float h0[100 * 8];   // [j][r]
    __shared__ float h1[100 * 8];               // [i][r]
    __shared__ float symL[24];

    int tid = threadIdx.x;
    int row0 = blockIdx.x * 8;

    if (tid < 24) symL[tid] = ymg[tid];
    __syncthreads();
    for (int e = tid; e < 192; e += 256) {
        int r = e / 24, c = e - r * 24;
        sX[r * 25 + c] = y1[row0 * 24 + e] - symL[c];
    }

    int ii = tid & 127, rg = tid >> 7;

    for (int pass = 0; pass < 2; ++pass) {
        const float* w0  = pass ? w0B  : w0A;
        const float* w1t = pass ? w1tB : w1tA;
        const float* w2  = pass ? w2B  : w2A;
        for (int t = tid; t < 2400; t += 256) {
            sw0[t] = w0[t];
            sw2[t] = w2[t];
        }
        __syncthreads();   // staging + sX ready

        // layer 0: h0[j][r], 800 outputs, weights from LDS
        for (int e = tid; e < 800; e += 256) {
            int j = e >> 3, r = e & 7;
            const float* wr = sw0 + j * 24;
            const float* xr = sX + r * 25;
            float a = 0.f, b = 0.f;
#pragma unroll
            for (int k = 0; k < 24; k += 2) {
                a = fmaf(wr[k],     xr[k],     a);
                b = fmaf(wr[k + 1], xr[k + 1], b);
            }
            h0[j * 8 + r] = splus(a + b);
        }
        __syncthreads();

        // layer 1: thread (rg, ii) -> z1[ii] for rows 4rg..4rg+3
        {
            float4 a = make_float4(0.f, 0.f, 0.f, 0.f);
            const float* wc = w1t + ii;
            const float4* h4 = (const float4*)h0 + rg;   // [j][2] float4
#pragma unroll 4
            for (int j = 0; j < 100; ++j) {
                float w = wc[j * 128];
                float4 h = h4[j * 2];
                a.x = fmaf(w, h.x, a.x); a.y = fmaf(w, h.y, a.y);
                a.z = fmaf(w, h.z, a.z); a.w = fmaf(w, h.w, a.w);
            }
            if (ii < 100) {
                h1[ii * 8 + rg * 4]     = splus(a.x);
                h1[ii * 8 + rg * 4 + 1] = splus(a.y);
                h1[ii * 8 + rg * 4 + 2] = splus(a.z);
                h1[ii * 8 + rg * 4 + 3] = splus(a.w);
            }
        }
        __syncthreads();

        // layer 2: 192 outputs, weights from LDS
        if (tid < 192) {
            int c = tid >> 3, r = tid & 7;
            const float* w2r = sw2 + c * 100;
            float s = 0.f, s2 = 0.f;
#pragma unroll 4
            for (int i = 0; i < 100; i += 2) {
                s  = fmaf(w2r[i],     h1[i * 8 + r],       s);
                s2 = fmaf(w2r[i + 1], h1[(i + 1) * 8 + r], s2);
            }
            float v = s + s2;
            if (pass == 0) sO[r * 25 + c] = v;
            else yhat1[(row0 + r) * 24 + c] = v + symL[c];
        }

        if (pass == 0) {
            __syncthreads();
            if (tid < 96) {
                int pr = tid >> 3, r = tid & 7;
                float v0 = sO[r * 25 + 2*pr], v1 = sO[r * 25 + 2*pr + 1];
                float q0, q1; hexq(v0, v1, q0, q1);
                yhat[(row0 + r) * 24 + 2*pr]     = q0;
                yhat[(row0 + r) * 24 + 2*pr + 1] = q1;
                sX[r * 25 + 2*pr]     = q0;       // pass-B input
                sX[r * 25 + 2*pr + 1] = q1;
            }
        }
    }
}

// ---------------------------------------------------------------------------
// K4: gs GEMM -> xhat
// ---------------------------------------------------------------------------
__global__ __launch_bounds__(256, 4) void k_gs(
    const float* __restrict__ yhat1,
    const float* __restrict__ w0, const float* __restrict__ b0,
    const float* __restrict__ w1t,
    const float* __restrict__ b1, const float* __restrict__ w2,
    const float* __restrict__ b2, float* __restrict__ xhat)
{
    gemm2_body<0>(blockIdx.x, yhat1, w0, b0, w1t, b1, w2, b2, xhat, nullptr);
}

// ---------------------------------------------------------------------------
// K5: MC likelihood via table gather; shuffle-based logsumexp.
// ---------------------------------------------------------------------------
__global__ __launch_bounds__(256) void k_mc_tbl(
    const float* __restrict__ yhat, const float* __restrict__ u2t,
    const float* __restrict__ eb,
    const float* __restrict__ tbl, float* __restrict__ lik)
{
    __shared__ float redm[4], reds[4];
    int tid = threadIdx.x;
    int wv = tid >> 6;
    int b = blockIdx.x;

    float y[24];
    const float4* yr = (const float4*)(yhat + b * 24);
#pragma unroll
    for (int k4 = 0; k4 < 6; ++k4) {
        float4 t = yr[k4];
        y[4*k4] = t.x; y[4*k4+1] = t.y; y[4*k4+2] = t.z; y[4*k4+3] = t.w;
    }

    float lp = 0.f;
    unsigned miss = 0;
#pragma unroll
    for (int c = 0; c < 24; ++c) {
        float inv = (c & 1) ? INV_ODD : 2.0f;
        int k = (int)rintf(y[c] * inv);
        int idx = k - KBASE;
        if (idx >= 0 && idx < TBL_CAP)
            lp += tbl[(c * TBL_CAP + idx) * 256 + tid];
        else
            miss |= (1u << c);
    }
    while (miss) {   // rare fallback: channel exceeded the fixed range
        int c = __ffs(miss) - 1;
        miss &= miss - 1;
        lp += logpdf_ch(eb + c * 58, y[c] + u2t[c * 256 + tid]);
    }

    float m = lp;
#pragma unroll
    for (int off = 1; off < 64; off <<= 1) m = fmaxf(m, __shfl_xor(m, off));
    if ((tid & 63) == 0) redm[wv] = m;
    __syncthreads();
    float mx = fmaxf(fmaxf(redm[0], redm[1]), fmaxf(redm[2], redm[3]));
    float e = __expf(lp - mx);
#pragma unroll
    for (int off = 1; off < 64; off <<= 1) e += __shfl_xor(e, off);
    if ((tid & 63) == 0) reds[wv] = e;
    __syncthreads();
    if (tid == 0)
        lik[b] = mx + __logf(reds[0] + reds[1] + reds[2] + reds[3])
               - 7.271269879190247f;  // -log(NMC) + LOG_VOL
}

// ---------------------------------------------------------------------------
// K5 fallback (ws too small): direct MC
// ---------------------------------------------------------------------------
__global__ __launch_bounds__(256) void k_mc_direct(
    const float* __restrict__ yhat, const float* __restrict__ u2t,
    const float* __restrict__ eb, float* __restrict__ lik)
{
    __shared__ alignas(16) float sU[24 * 256];
    __shared__ float redm[4], reds[4];
    int tid = threadIdx.x;
    int wv = tid >> 6;
    int b = blockIdx.x;
    for (int i = tid; i < 1536; i += 256)
        ((float4*)sU)[i] = ((const float4*)u2t)[i];
    __syncthreads();

    float lp = 0.f;
    for (int c = 0; c < 24; ++c)
        lp += logpdf_ch(eb + c * 58, yhat[b * 24 + c] + sU[c * 256 + tid]);

    float m = lp;
#pragma unroll
    for (int off = 1; off < 64; off <<= 1) m = fmaxf(m, __shfl_xor(m, off));
    if ((tid & 63) == 0) redm[wv] = m;
    __syncthreads();
    float mx = fmaxf(fmaxf(redm[0], redm[1]), fmaxf(redm[2], redm[3]));
    float e = __expf(lp - mx);
#pragma unroll
    for (int off = 1; off < 64; off <<= 1) e += __shfl_xor(e, off);
    if ((tid & 63) == 0) reds[wv] = e;
    __syncthreads();
    if (tid == 0)
        lik[b] = mx + __logf(reds[0] + reds[1] + reds[2] + reds[3])
               - 7.271269879190247f;
}

// ---------------------------------------------------------------------------
extern "C" void kernel_launch(void* const* d_in, const int* in_sizes, int n_in,
                              void* d_out, int out_size, void* d_ws, size_t ws_size,
                              hipStream_t stream)
{
    (void)in_sizes; (void)n_in; (void)out_size;
    const float* x      = (const float*)d_in[0];
    const float* y_mean = (const float*)d_in[1];
    const float* u      = (const float*)d_in[2];
    const float* ga_w0  = (const float*)d_in[3];
    const float* ga_b0  = (const float*)d_in[4];
    const float* ga_w1  = (const float*)d_in[5];
    const float* ga_b1  = (const float*)d_in[6];
    const float* ga_w2  = (const float*)d_in[7];
    const float* ga_b2  = (const float*)d_in[8];
    const float* gs_w0  = (const float*)d_in[9];
    const float* gs_b0  = (const float*)d_in[10];
    const float* gs_w1  = (const float*)d_in[11];
    const float* gs_b1  = (const float*)d_in[12];
    const float* gs_w2  = (const float*)d_in[13];
    const float* gs_b2  = (const float*)d_in[14];
    const float* gac_w0 = (const float*)d_in[15];
    const float* gac_w1 = (const float*)d_in[16];
    const float* gac_w2 = (const float*)d_in[17];
    const float* gsc_w0 = (const float*)d_in[18];
    const float* gsc_w1 = (const float*)d_in[19];
    const float* gsc_w2 = (const float*)d_in[20];
    const float* eb_H0  = (const float*)d_in[21];
    const float* eb_H1  = (const float*)d_in[22];
    const float* eb_H2  = (const float*)d_in[23];
    const float* eb_H3  = (const float*)d_in[24];
    const float* eb_H4  = (const float*)d_in[25];
    const float* eb_b0  = (const float*)d_in[26];
    const float* eb_b1  = (const float*)d_in[27];
    const float* eb_b2  = (const float*)d_in[28];
    const float* eb_b3  = (const float*)d_in[29];
    const float* eb_b4  = (const float*)d_in[30];
    const float* eb_a0  = (const float*)d_in[31];
    const float* eb_a1  = (const float*)d_in[32];
    const float* eb_a2  = (const float*)d_in[33];
    const float* eb_a3  = (const float*)d_in[34];

    float* ws    = (float*)d_ws;
    float* y1    = ws + WS_Y1;
    float* yhat  = ws + WS_YHAT;
    float* yhat1 = ws + WS_YHAT1;
    float* ym    = ws + WS_YM;
    float* u2t   = ws + WS_U2T;
    float* eb    = ws + WS_EB;
    float* part  = ws + WS_PART;
    float* w1t   = ws + WS_W1T;
    float* tbl   = ws + WS_TBL;
    float* xhat  = (float*)d_out;
    float* lik   = (float*)d_out + 98304;

    float* w1tGA  = w1t;
    float* w1tGAC = w1t + 12800;
    float* w1tGSC = w1t + 25600;
    float* w1tGS  = w1t + 38400;

    bool use_tbl = ws_size >= WS_END * sizeof(float);

    k_prep<<<201, 256, 0, stream>>>(eb_H0, eb_H1, eb_H2, eb_H3, eb_H4,
                                    eb_b0, eb_b1, eb_b2, eb_b3, eb_b4,
                                    eb_a0, eb_a1, eb_a2, eb_a3, u,
                                    ga_w1, gac_w1, gsc_w1, gs_w1,
                                    eb, u2t, w1t);
    if (use_tbl)
        k_ga_table<<<G2_BLOCKS + 24 * TBL_CAP, 256, 0, stream>>>(
            x, ga_w0, ga_b0, w1tGA, ga_b1, ga_w2, ga_b2, y1, part,
            eb, u2t, tbl);
    else
        k_ga_table<<<G2_BLOCKS, 256, 0, stream>>>(
            x, ga_w0, ga_b0, w1tGA, ga_b1, ga_w2, ga_b2, y1, part,
            eb, u2t, tbl);
    k_mean_final<<<1, 256, 0, stream>>>(part, y_mean, ym);
    k_fused24<<<NB / 8, 256, 0, stream>>>(y1, gac_w0, w1tGAC, gac_w2,
                                          gsc_w0, w1tGSC, gsc_w2,
                                          ym, yhat, yhat1);
    k_gs<<<G2_BLOCKS, 256, 0, stream>>>(yhat1, gs_w0, gs_b0, w1tGS,
                                        gs_b1, gs_w2, gs_b2, xhat);
    if (use_tbl)
        k_mc_tbl<<<NB, 256, 0, stream>>>(yhat, u2t, eb, tbl, lik);
    else
        k_mc_direct<<<NB, 256, 0, stream>>>(yhat, u2t, eb, lik);
}

// Round 10
// 121.264 us; speedup vs baseline: 1.2090x; 1.0875x over previous
//
#include <hip/hip_runtime.h>
#include <hip/hip_bf16.h>
#include <math.h>
#include <limits.h>

// Problem dims
constexpr int NB    = 4096;   // batch
constexpr int ROWS2 = NB * 12;            // 49152 rows for the 2->100->100->2 MLPs
constexpr int G2_BLOCKS = ROWS2 / 64;     // 768 (64 rows/block)
constexpr int TBL_CAP = 64;               // lattice slots per channel (fixed range)
constexpr int KBASE   = -32;              // fixed kmin for all channels

// workspace layout (float offsets)
constexpr size_t WS_Y1    = 0;              // NB*24
constexpr size_t WS_YHAT  = 98304;          // NB*24
constexpr size_t WS_YHAT1 = 196608;         // NB*24
constexpr size_t WS_YM    = 294912;         // 24
constexpr size_t WS_U2T   = 294936;         // 24*256 (transposed: [c][m])
constexpr size_t WS_EB    = 301080;         // 24*58 precomputed prior params
constexpr size_t WS_PART  = 302472;         // 768*24 per-block mean partials
constexpr size_t WS_W1T   = 320904;         // 2 x [100][128] transposed w1 (region 51200)
constexpr size_t WS_TBL   = 372104;         // 24*64*256 table of log(pdf+1e-9)
constexpr size_t WS_END   = WS_TBL + 24 * TBL_CAP * 256;   // 765320 floats (~3.06 MB)

constexpr float STEP_ODD = 0.8660254037844386f;   // sqrt(3)/2
constexpr float INV_ODD  = 1.1547005383792517f;   // 2/sqrt(3)

__device__ __forceinline__ float lrelu(float x) { return x >= 0.f ? x : 0.01f * x; }
__device__ __forceinline__ float rcp_fast(float x) { return __builtin_amdgcn_rcpf(x); }

__device__ __forceinline__ float tanh_fast(float x) {
    float xx = fminf(fmaxf(x, -15.f), 15.f);
    float e = __expf(xx + xx);
    return fmaf(-2.f, rcp_fast(e + 1.f), 1.f);
}
__device__ __forceinline__ float splus(float x) {
    return fmaxf(x, 0.f) + __logf(1.f + __expf(-fabsf(x)));
}
__device__ __forceinline__ float splus_precise(float x) {
    return fmaxf(x, 0.f) + log1pf(expf(-fabsf(x)));
}

__device__ __forceinline__ void fma4(float4& a, float h, const float4& w) {
    a.x = fmaf(h, w.x, a.x); a.y = fmaf(h, w.y, a.y);
    a.z = fmaf(h, w.z, a.z); a.w = fmaf(h, w.w, a.w);
}

// exact A2 hex lattice nearest-point quantizer; matches jnp.round (rint = RNE)
__device__ __forceinline__ void hexq(float p0, float p1, float& q0, float& q1) {
    const float S3 = 1.7320508075688772f;
    const float H3 = 0.8660254037844386f;
    float c00 = rintf(p0);
    float c01 = rintf(p1 / S3) * S3;
    float c10 = rintf(p0 - 0.5f) + 0.5f;
    float c11 = rintf((p1 - H3) / S3) * S3 + H3;
    float d0 = (p0 - c00) * (p0 - c00) + (p1 - c01) * (p1 - c01);
    float d1 = (p0 - c10) * (p0 - c10) + (p1 - c11) * (p1 - c11);
    bool take0 = d0 <= d1;
    q0 = take0 ? c00 : c10;
    q1 = take0 ? c01 : c11;
}

// per-channel prior chain: log(pdf + 1e-9) at point p, params P (58 floats)
__device__ __forceinline__ float logpdf_ch(const float* __restrict__ P, float p) {
    float w00 = P[0], w01 = P[1], w02 = P[2];
    float z0 = fmaf(w00, p, P[3]);
    float z1 = fmaf(w01, p, P[4]);
    float z2 = fmaf(w02, p, P[5]);
    float a0 = P[6], a1 = P[7], a2 = P[8];
    float e0 = tanh_fast(z0), e1 = tanh_fast(z1), e2 = tanh_fast(z2);
    float h0 = fmaf(a0, e0, z0), h1 = fmaf(a1, e1, z1), h2 = fmaf(a2, e2, z2);
    float t0 = w00 * fmaf(a0, fmaf(-e0, e0, 1.f), 1.f);
    float t1 = w01 * fmaf(a1, fmaf(-e1, e1, 1.f), 1.f);
    float t2 = w02 * fmaf(a2, fmaf(-e2, e2, 1.f), 1.f);

#define EB_LAYER(O)                                                            \
    {                                                                          \
        float z0n = fmaf(P[O+0], h0, fmaf(P[O+1], h1, fmaf(P[O+2], h2, P[O+9])));  \
        float z1n = fmaf(P[O+3], h0, fmaf(P[O+4], h1, fmaf(P[O+5], h2, P[O+10]))); \
        float z2n = fmaf(P[O+6], h0, fmaf(P[O+7], h1, fmaf(P[O+8], h2, P[O+11]))); \
        float s0 = fmaf(P[O+0], t0, fmaf(P[O+1], t1, P[O+2] * t2));            \
        float s1 = fmaf(P[O+3], t0, fmaf(P[O+4], t1, P[O+5] * t2));            \
        float s2 = fmaf(P[O+6], t0, fmaf(P[O+7], t1, P[O+8] * t2));            \
        float g0 = P[O+12], g1 = P[O+13], g2 = P[O+14];                        \
        float q0 = tanh_fast(z0n), q1 = tanh_fast(z1n), q2 = tanh_fast(z2n);   \
        h0 = fmaf(g0, q0, z0n); h1 = fmaf(g1, q1, z1n); h2 = fmaf(g2, q2, z2n); \
        t0 = s0 * fmaf(g0, fmaf(-q0, q0, 1.f), 1.f);                           \
        t1 = s1 * fmaf(g1, fmaf(-q1, q1, 1.f), 1.f);                           \
        t2 = s2 * fmaf(g2, fmaf(-q2, q2, 1.f), 1.f);                           \
    }
    EB_LAYER(9)
    EB_LAYER(24)
    EB_LAYER(39)
#undef EB_LAYER

    float L = fmaf(P[54], h0, fmaf(P[55], h1, fmaf(P[56], h2, P[57])));
    float T = fmaf(P[54], t0, fmaf(P[55], t1, P[56] * t2));
    float Lc = fminf(fmaxf(L, -30.f), 30.f);
    float sg = rcp_fast(1.f + __expf(-Lc));
    float pdf = sg * (1.f - sg) * T;
    return __logf(pdf + 1e-9f);
}

// ---------------------------------------------------------------------------
// K0: block 0: prior params + u2^T.
//     blocks 1..100: transpose ga_w1/gs_w1 into [100][128] zero-padded.
// ---------------------------------------------------------------------------
__global__ __launch_bounds__(256) void k_prep(
    const float* __restrict__ H0p, const float* __restrict__ H1p,
    const float* __restrict__ H2p, const float* __restrict__ H3p,
    const float* __restrict__ H4p,
    const float* __restrict__ b0p, const float* __restrict__ b1p,
    const float* __restrict__ b2p, const float* __restrict__ b3p,
    const float* __restrict__ b4p,
    const float* __restrict__ a0p, const float* __restrict__ a1p,
    const float* __restrict__ a2p, const float* __restrict__ a3p,
    const float* __restrict__ u,
    const float* __restrict__ w1ga, const float* __restrict__ w1gs,
    float* __restrict__ eb, float* __restrict__ u2t,
    float* __restrict__ w1t)
{
    int tid = threadIdx.x;
    if (blockIdx.x > 0) {
        int t = blockIdx.x - 1;             // 0..99
        int m = t / 50;
        int o = (t % 50) * 256 + tid;       // 0..12799
        int k = o >> 7, i = o & 127;
        const float* src = (m == 0) ? w1ga : w1gs;
        w1t[m * 12800 + o] = (i < 100) ? src[i * 100 + k] : 0.f;
        return;
    }
    if (tid < 24) {
        int c = tid;
        float* P = eb + c * 58;
        for (int j = 0; j < 3; ++j) P[j]      = splus_precise(H0p[c*3+j]);
        for (int j = 0; j < 3; ++j) P[3+j]    = b0p[c*3+j];
        for (int j = 0; j < 3; ++j) P[6+j]    = tanhf(a0p[c*3+j]);
        for (int j = 0; j < 9; ++j) P[9+j]    = splus_precise(H1p[c*9+j]);
        for (int j = 0; j < 3; ++j) P[18+j]   = b1p[c*3+j];
        for (int j = 0; j < 3; ++j) P[21+j]   = tanhf(a1p[c*3+j]);
        for (int j = 0; j < 9; ++j) P[24+j]   = splus_precise(H2p[c*9+j]);
        for (int j = 0; j < 3; ++j) P[33+j]   = b2p[c*3+j];
        for (int j = 0; j < 3; ++j) P[36+j]   = tanhf(a2p[c*3+j]);
        for (int j = 0; j < 9; ++j) P[39+j]   = splus_precise(H3p[c*9+j]);
        for (int j = 0; j < 3; ++j) P[48+j]   = b3p[c*3+j];
        for (int j = 0; j < 3; ++j) P[51+j]   = tanhf(a3p[c*3+j]);
        for (int j = 0; j < 3; ++j) P[54+j]   = splus_precise(H4p[c*3+j]);
        P[57] = b4p[c];
    }
    int m = tid;
    if (m < 256) {
        for (int j = 0; j < 12; ++j) {
            float a  = u[m*24 + 2*j];
            float bb = u[m*24 + 2*j + 1];
            float p0 = fmaf(0.5f, bb, a);
            float p1 = 0.8660254037844386f * bb;
            float q0, q1; hexq(p0, p1, q0, q1);
            u2t[(2*j)   * 256 + m] = p0 - q0;
            u2t[(2*j+1) * 256 + m] = p1 - q1;
        }
    }
}

// ---------------------------------------------------------------------------
// gemm2 body: 2 -> 100 (lrelu) -> 100 (lrelu) -> 2, register-tiled, weights
// streamed from L2 (pre-transposed w1t [100][128]) with explicit 2-deep
// register prefetch; only h0^T in LDS.
// ---------------------------------------------------------------------------
template <int MEAN>
__device__ __forceinline__ void gemm2_body(
    int bid,
    const float* __restrict__ in,
    const float* __restrict__ w0, const float* __restrict__ b0,
    const float* __restrict__ w1t,
    const float* __restrict__ b1, const float* __restrict__ w2,
    const float* __restrict__ b2,
    float* __restrict__ out, float* __restrict__ partial)
{
    __shared__ alignas(16) float shT[100 * 64];   // h0T [k][row]; reused as red
    __shared__ float S[64][2];

    int tid = threadIdx.x;
    int row0 = bid * 64;

    int lrow = tid & 63, jg = tid >> 6;
    float2 xv = ((const float2*)in)[row0 + lrow];
#pragma unroll
    for (int jj = 0; jj < 25; ++jj) {
        int j = jg * 25 + jj;
        shT[j * 64 + lrow] =
            lrelu(fmaf(w0[2*j], xv.x, fmaf(w0[2*j+1], xv.y, b0[j])));
    }

    int lane = tid & 63, wv = tid >> 6;
    int ct = lane & 31;                 // col group: cols 4ct..4ct+3 of 128
    int rt = wv * 2 + (lane >> 5);      // row group: rows 8rt..8rt+7
    bool cvalid = (4 * ct < 100);
    float4 zero4 = make_float4(0.f, 0.f, 0.f, 0.f);
    float4 b14 = cvalid ? *(const float4*)(b1 + 4*ct) : zero4;
    float4 w20 = cvalid ? *(const float4*)(w2 + 4*ct) : zero4;
    float4 w21 = cvalid ? *(const float4*)(w2 + 100 + 4*ct) : zero4;
    __syncthreads();

    float4 acc[8];
#pragma unroll
    for (int r = 0; r < 8; ++r) acc[r] = zero4;
    const float4* wg  = (const float4*)w1t + ct;   // +32 float4 per k
    const float4* hT4 = (const float4*)shT;        // [100][16]
    // 2-deep rotating prefetch (reads 2 rows past end land in reserved ws)
    float4 wa = wg[0];
    float4 wb = wg[32];
#pragma unroll 4
    for (int k = 0; k < 100; ++k) {
        float4 wn = wg[(k + 2) * 32];
        float4 ha = hT4[k * 16 + rt * 2];
        float4 hb = hT4[k * 16 + rt * 2 + 1];
        fma4(acc[0], ha.x, wa); fma4(acc[1], ha.y, wa);
        fma4(acc[2], ha.z, wa); fma4(acc[3], ha.w, wa);
        fma4(acc[4], hb.x, wa); fma4(acc[5], hb.y, wa);
        fma4(acc[6], hb.z, wa); fma4(acc[7], hb.w, wa);
        wa = wb; wb = wn;
    }
    __syncthreads();          // h reads done; reuse shT as reduction pad

    float* red = shT;         // [64][2][32]
#pragma unroll
    for (int r = 0; r < 8; ++r) {
        float a0 = lrelu(acc[r].x + b14.x);
        float a1 = lrelu(acc[r].y + b14.y);
        float a2 = lrelu(acc[r].z + b14.z);
        float a3 = lrelu(acc[r].w + b14.w);
        float y0 = fmaf(a0, w20.x, fmaf(a1, w20.y, fmaf(a2, w20.z, a3 * w20.w)));
        float y1 = fmaf(a0, w21.x, fmaf(a1, w21.y, fmaf(a2, w21.z, a3 * w21.w)));
        int row = rt * 8 + r;
        red[(row * 2) * 32 + ct]     = y0;
        red[(row * 2 + 1) * 32 + ct] = y1;
    }
    __syncthreads();
    if (tid < 128) {
        int row = tid >> 1, p = tid & 1;
        const float4* rp = (const float4*)&red[(row * 2 + p) * 32];
        float s = 0.f;
#pragma unroll
        for (int g = 0; g < 8; ++g) {
            float4 v = rp[g];
            s += (v.x + v.y) + (v.z + v.w);
        }
        float y = s + b2[p];
        out[(row0 + row) * 2 + p] = y;
        if (MEAN) S[row][p] = y;
    }
    if (MEAN) {
        __syncthreads();
        if (tid < 24) {
            int j = tid >> 1, par = tid & 1;
            int base = row0 % 12;
            int k0 = (j - base + 12) % 12;
            float s = 0.f;
            for (int k = k0; k < 64; k += 12) s += S[k][par];
            partial[bid * 24 + tid] = s;
        }
    }
}

// ---------------------------------------------------------------------------
// K1: merged dispatch: blocks [0,768) = ga GEMM (y1 + mean partials),
// blocks [768, 768+1536) = prior table build (fixed range, needs only prep).
// ---------------------------------------------------------------------------
__global__ __launch_bounds__(256, 4) void k_ga_table(
    const float* __restrict__ in,
    const float* __restrict__ w0, const float* __restrict__ b0,
    const float* __restrict__ w1t,
    const float* __restrict__ b1, const float* __restrict__ w2,
    const float* __restrict__ b2,
    float* __restrict__ out, float* __restrict__ partial,
    const float* __restrict__ eb, const float* __restrict__ u2t,
    float* __restrict__ tbl)
{
    if (blockIdx.x < (unsigned)G2_BLOCKS) {
        gemm2_body<1>(blockIdx.x, in, w0, b0, w1t, b1, w2, b2, out, partial);
    } else {
        int cv = blockIdx.x - G2_BLOCKS;
        int c = cv >> 6, v = cv & 63;
        int m = threadIdx.x;
        float step = (c & 1) ? STEP_ODD : 0.5f;
        float val = (float)(KBASE + v) * step;
        float p = val + u2t[c * 256 + m];
        tbl[cv * 256 + m] = logpdf_ch(eb + c * 58, p);
    }
}

// ---------------------------------------------------------------------------
// K2: finish the EMA mean from 768 per-block partials (1 block, sub-us)
// ---------------------------------------------------------------------------
__global__ __launch_bounds__(256) void k_mean_final(
    const float* __restrict__ partial, const float* __restrict__ y_mean,
    float* __restrict__ ym)
{
    int tid = threadIdx.x;
    int c = tid >> 3, s = tid & 7;
    float v = 0.f;
    if (c < 24)
        for (int g = s; g < G2_BLOCKS; g += 8) v += partial[g * 24 + c];
    v += __shfl_xor(v, 1); v += __shfl_xor(v, 2); v += __shfl_xor(v, 4);
    if (c < 24 && s == 0)
        ym[c] = fmaf(0.05f, y_mean[c], 0.95f * (v * (1.0f / NB)));
}

// ---------------------------------------------------------------------------
// K3: FUSED coupled transforms. 8 rows/block, 512 blocks.
// Layer-1 reads the ORIGINAL w1 (row ii contiguous): 25 float4 loads/thread,
// 16 FMA per load. w0/w2 staged in LDS. Bit-identical j-order accumulation.
// Pass A: yhat = hexq(gac(y1-ym)).  Pass B: yhat1 = gsc(yhat) + ym.
// ---------------------------------------------------------------------------
__global__ __launch_bounds__(256, 4) void k_fused24(
    const float* __restrict__ y1,
    const float* __restrict__ w0A, const float* __restrict__ w1A,
    const float* __restrict__ w2A,
    const float* __restrict__ w0B, const float* __restrict__ w1B,
    const float* __restrict__ w2B,
    const float* __restrict__ ymg,
    float* __restrict__ yhat, float* __restrict__ yhat1)
{
    __shared__ float sw0[2400];
    __shared__ float sw2[2400];
    __shared__ float sX[8 * 25];
    __shared__ float sO[8 * 25];
    __shared__ alignas(16) float h0[100 * 8];   // [j][r]
    __shared__ float h1[100 * 8];               // [i][r]
    __shared__ float symL[24];

    int tid = threadIdx.x;
    int row0 = blockIdx.x * 8;

    if (tid < 24) symL[tid] = ymg[tid];
    __syncthreads();
    for (int e = tid; e < 192; e += 256) {
        int r = e / 24, c = e - r * 24;
        sX[r * 25 + c] = y1[row0 * 24 + e] - symL[c];
    }

    int ii = tid & 127, rg = tid >> 7;

    for (int pass = 0; pass < 2; ++pass) {
        const float* w0  = pass ? w0B  : w0A;
        const float* w1  = pass ? w1B  : w1A;
        const float* w2  = pass ? w2B  : w2A;
        for (int t = tid; t < 2400; t += 256) {
            sw0[t] = w0[t];
            sw2[t] = w2[t];
        }
        __syncthreads();   // staging + sX ready

        // layer 0: h0[j][r], 800 outputs, weights from LDS
        for (int e = tid; e < 800; e += 256) {
            int j = e >> 3, r = e & 7;
            const float* wr = sw0 + j * 24;
            const float* xr = sX + r * 25;
            float a = 0.f, b = 0.f;
#pragma unroll
            for (int k = 0; k < 24; k += 2) {
                a = fmaf(wr[k],     xr[k],     a);
                b = fmaf(wr[k + 1], xr[k + 1], b);
            }
            h0[j * 8 + r] = splus(a + b);
        }
        __syncthreads();

        // layer 1: thread (rg, ii) -> z1[ii] for rows 4rg..4rg+3
        if (ii < 100) {
            float4 a = make_float4(0.f, 0.f, 0.f, 0.f);
            const float4* wr = (const float4*)(w1 + ii * 100);  // 25 float4
            const float4* h4 = (const float4*)h0 + rg;          // [j][2] f4
#pragma unroll 5
            for (int j4 = 0; j4 < 25; ++j4) {
                float4 wv = wr[j4];
                float4 ha = h4[(4*j4)     * 2];
                float4 hb = h4[(4*j4 + 1) * 2];
                float4 hc = h4[(4*j4 + 2) * 2];
                float4 hd = h4[(4*j4 + 3) * 2];
                fma4(a, wv.x, ha);
                fma4(a, wv.y, hb);
                fma4(a, wv.z, hc);
                fma4(a, wv.w, hd);
            }
            h1[ii * 8 + rg * 4]     = splus(a.x);
            h1[ii * 8 + rg * 4 + 1] = splus(a.y);
            h1[ii * 8 + rg * 4 + 2] = splus(a.z);
            h1[ii * 8 + rg * 4 + 3] = splus(a.w);
        }
        __syncthreads();

        // layer 2: 192 outputs, weights from LDS
        if (tid < 192) {
            int c = tid >> 3, r = tid & 7;
            const float* w2r = sw2 + c * 100;
            float s = 0.f, s2 = 0.f;
#pragma unroll 4
            for (int i = 0; i < 100; i += 2) {
                s  = fmaf(w2r[i],     h1[i * 8 + r],       s);
                s2 = fmaf(w2r[i + 1], h1[(i + 1) * 8 + r], s2);
            }
            float v = s + s2;
            if (pass == 0) sO[r * 25 + c] = v;
            else yhat1[(row0 + r) * 24 + c] = v + symL[c];
        }

        if (pass == 0) {
            __syncthreads();
            if (tid < 96) {
                int pr = tid >> 3, r = tid & 7;
                float v0 = sO[r * 25 + 2*pr], v1 = sO[r * 25 + 2*pr + 1];
                float q0, q1; hexq(v0, v1, q0, q1);
                yhat[(row0 + r) * 24 + 2*pr]     = q0;
                yhat[(row0 + r) * 24 + 2*pr + 1] = q1;
                sX[r * 25 + 2*pr]     = q0;       // pass-B input
                sX[r * 25 + 2*pr + 1] = q1;
            }
        }
    }
}

// ---------------------------------------------------------------------------
// K4 (merged): blocks [0,768) = gs GEMM -> xhat; blocks [768,768+4096) =
// MC likelihood via table gather. Both depend only on k_fused24.
// ---------------------------------------------------------------------------
__global__ __launch_bounds__(256, 4) void k_gs_mc(
    const float* __restrict__ yhat1,
    const float* __restrict__ w0, const float* __restrict__ b0,
    const float* __restrict__ w1t,
    const float* __restrict__ b1, const float* __restrict__ w2,
    const float* __restrict__ b2, float* __restrict__ xhat,
    const float* __restrict__ yhat, const float* __restrict__ u2t,
    const float* __restrict__ eb,
    const float* __restrict__ tbl, float* __restrict__ lik)
{
    if (blockIdx.x < (unsigned)G2_BLOCKS) {
        gemm2_body<0>(blockIdx.x, yhat1, w0, b0, w1t, b1, w2, b2, xhat, nullptr);
        return;
    }
    __shared__ float redm[4], reds[4];
    int tid = threadIdx.x;
    int wv = tid >> 6;
    int b = blockIdx.x - G2_BLOCKS;

    float y[24];
    const float4* yr = (const float4*)(yhat + b * 24);
#pragma unroll
    for (int k4 = 0; k4 < 6; ++k4) {
        float4 t = yr[k4];
        y[4*k4] = t.x; y[4*k4+1] = t.y; y[4*k4+2] = t.z; y[4*k4+3] = t.w;
    }

    float lp = 0.f;
    unsigned miss = 0;
#pragma unroll
    for (int c = 0; c < 24; ++c) {
        float inv = (c & 1) ? INV_ODD : 2.0f;
        int k = (int)rintf(y[c] * inv);
        int idx = k - KBASE;
        if (idx >= 0 && idx < TBL_CAP)
            lp += tbl[(c * TBL_CAP + idx) * 256 + tid];
        else
            miss |= (1u << c);
    }
    while (miss) {   // rare fallback: channel exceeded the fixed range
        int c = __ffs(miss) - 1;
        miss &= miss - 1;
        lp += logpdf_ch(eb + c * 58, y[c] + u2t[c * 256 + tid]);
    }

    float m = lp;
#pragma unroll
    for (int off = 1; off < 64; off <<= 1) m = fmaxf(m, __shfl_xor(m, off));
    if ((tid & 63) == 0) redm[wv] = m;
    __syncthreads();
    float mx = fmaxf(fmaxf(redm[0], redm[1]), fmaxf(redm[2], redm[3]));
    float e = __expf(lp - mx);
#pragma unroll
    for (int off = 1; off < 64; off <<= 1) e += __shfl_xor(e, off);
    if ((tid & 63) == 0) reds[wv] = e;
    __syncthreads();
    if (tid == 0)
        lik[b] = mx + __logf(reds[0] + reds[1] + reds[2] + reds[3])
               - 7.271269879190247f;  // -log(NMC) + LOG_VOL
}

// ---------------------------------------------------------------------------
// Fallback path kernels (ws too small for the table)
// ---------------------------------------------------------------------------
__global__ __launch_bounds__(256, 4) void k_gs(
    const float* __restrict__ yhat1,
    const float* __restrict__ w0, const float* __restrict__ b0,
    const float* __restrict__ w1t,
    const float* __restrict__ b1, const float* __restrict__ w2,
    const float* __restrict__ b2, float* __restrict__ xhat)
{
    gemm2_body<0>(blockIdx.x, yhat1, w0, b0, w1t, b1, w2, b2, xhat, nullptr);
}

__global__ __launch_bounds__(256) void k_mc_direct(
    const float* __restrict__ yhat, const float* __restrict__ u2t,
    const float* __restrict__ eb, float* __restrict__ lik)
{
    __shared__ alignas(16) float sU[24 * 256];
    __shared__ float redm[4], reds[4];
    int tid = threadIdx.x;
    int wv = tid >> 6;
    int b = blockIdx.x;
    for (int i = tid; i < 1536; i += 256)
        ((float4*)sU)[i] = ((const float4*)u2t)[i];
    __syncthreads();

    float lp = 0.f;
    for (int c = 0; c < 24; ++c)
        lp += logpdf_ch(eb + c * 58, yhat[b * 24 + c] + sU[c * 256 + tid]);

    float m = lp;
#pragma unroll
    for (int off = 1; off < 64; off <<= 1) m = fmaxf(m, __shfl_xor(m, off));
    if ((tid & 63) == 0) redm[wv] = m;
    __syncthreads();
    float mx = fmaxf(fmaxf(redm[0], redm[1]), fmaxf(redm[2], redm[3]));
    float e = __expf(lp - mx);
#pragma unroll
    for (int off = 1; off < 64; off <<= 1) e += __shfl_xor(e, off);
    if ((tid & 63) == 0) reds[wv] = e;
    __syncthreads();
    if (tid == 0)
        lik[b] = mx + __logf(reds[0] + reds[1] + reds[2] + reds[3])
               - 7.271269879190247f;
}

// ---------------------------------------------------------------------------
extern "C" void kernel_launch(void* const* d_in, const int* in_sizes, int n_in,
                              void* d_out, int out_size, void* d_ws, size_t ws_size,
                              hipStream_t stream)
{
    (void)in_sizes; (void)n_in; (void)out_size;
    const float* x      = (const float*)d_in[0];
    const float* y_mean = (const float*)d_in[1];
    const float* u      = (const float*)d_in[2];
    const float* ga_w0  = (const float*)d_in[3];
    const float* ga_b0  = (const float*)d_in[4];
    const float* ga_w1  = (const float*)d_in[5];
    const float* ga_b1  = (const float*)d_in[6];
    const float* ga_w2  = (const float*)d_in[7];
    const float* ga_b2  = (const float*)d_in[8];
    const float* gs_w0  = (const float*)d_in[9];
    const float* gs_b0  = (const float*)d_in[10];
    const float* gs_w1  = (const float*)d_in[11];
    const float* gs_b1  = (const float*)d_in[12];
    const float* gs_w2  = (const float*)d_in[13];
    const float* gs_b2  = (const float*)d_in[14];
    const float* gac_w0 = (const float*)d_in[15];
    const float* gac_w1 = (const float*)d_in[16];
    const float* gac_w2 = (const float*)d_in[17];
    const float* gsc_w0 = (const float*)d_in[18];
    const float* gsc_w1 = (const float*)d_in[19];
    const float* gsc_w2 = (const float*)d_in[20];
    const float* eb_H0  = (const float*)d_in[21];
    const float* eb_H1  = (const float*)d_in[22];
    const float* eb_H2  = (const float*)d_in[23];
    const float* eb_H3  = (const float*)d_in[24];
    const float* eb_H4  = (const float*)d_in[25];
    const float* eb_b0  = (const float*)d_in[26];
    const float* eb_b1  = (const float*)d_in[27];
    const float* eb_b2  = (const float*)d_in[28];
    const float* eb_b3  = (const float*)d_in[29];
    const float* eb_b4  = (const float*)d_in[30];
    const float* eb_a0  = (const float*)d_in[31];
    const float* eb_a1  = (const float*)d_in[32];
    const float* eb_a2  = (const float*)d_in[33];
    const float* eb_a3  = (const float*)d_in[34];

    float* ws    = (float*)d_ws;
    float* y1    = ws + WS_Y1;
    float* yhat  = ws + WS_YHAT;
    float* yhat1 = ws + WS_YHAT1;
    float* ym    = ws + WS_YM;
    float* u2t   = ws + WS_U2T;
    float* eb    = ws + WS_EB;
    float* part  = ws + WS_PART;
    float* w1t   = ws + WS_W1T;
    float* tbl   = ws + WS_TBL;
    float* xhat  = (float*)d_out;
    float* lik   = (float*)d_out + 98304;

    float* w1tGA = w1t;
    float* w1tGS = w1t + 12800;

    bool use_tbl = ws_size >= WS_END * sizeof(float);

    k_prep<<<101, 256, 0, stream>>>(eb_H0, eb_H1, eb_H2, eb_H3, eb_H4,
                                    eb_b0, eb_b1, eb_b2, eb_b3, eb_b4,
                                    eb_a0, eb_a1, eb_a2, eb_a3, u,
                                    ga_w1, gs_w1, eb, u2t, w1t);
    if (use_tbl)
        k_ga_table<<<G2_BLOCKS + 24 * TBL_CAP, 256, 0, stream>>>(
            x, ga_w0, ga_b0, w1tGA, ga_b1, ga_w2, ga_b2, y1, part,
            eb, u2t, tbl);
    else
        k_ga_table<<<G2_BLOCKS, 256, 0, stream>>>(
            x, ga_w0, ga_b0, w1tGA, ga_b1, ga_w2, ga_b2, y1, part,
            eb, u2t, tbl);
    k_mean_final<<<1, 256, 0, stream>>>(part, y_mean, ym);
    k_fused24<<<NB / 8, 256, 0, stream>>>(y1, gac_w0, gac_w1, gac_w2,
                                          gsc_w0, gsc_w1, gsc_w2,
                                          ym, yhat, yhat1);
    if (use_tbl) {
        k_gs_mc<<<G2_BLOCKS + NB, 256, 0, stream>>>(
            yhat1, gs_w0, gs_b0, w1tGS, gs_b1, gs_w2, gs_b2, xhat,
            yhat, u2t, eb, tbl, lik);
    } else {
        k_gs<<<G2_BLOCKS, 256, 0, stream>>>(
            yhat1, gs_w0, gs_b0, w1tGS, gs_b1, gs_w2, gs_b2, xhat);
        k_mc_direct<<<NB, 256, 0, stream>>>(yhat, u2t, eb, lik);
    }
}